// Round 1
// baseline (5647.831 us; speedup 1.0000x reference)
//
#include <hip/hip_runtime.h>

// GCN: 2-layer graph conv + graph mean-pool + linear head.
// N=500000 nodes, E=10000000 edges, H=8, G=1000 graphs, C=8. All fp32.

#define TB 256

__global__ void deg_kernel(const int* __restrict__ src, const int* __restrict__ dst,
                           float* __restrict__ deg_out, float* __restrict__ deg_in, int E) {
    int i = blockIdx.x * TB + threadIdx.x;
    if (i < E) {
        atomicAdd(&deg_out[src[i]], 1.0f);
        atomicAdd(&deg_in[dst[i]], 1.0f);
    }
}

__global__ void node_prep_kernel(const float* __restrict__ deg_in, const float* __restrict__ deg_out,
                                 float* __restrict__ isi, float* __restrict__ iso,
                                 float* __restrict__ h0s, int N) {
    int i = blockIdx.x * TB + threadIdx.x;
    if (i < N) {
        float di = deg_in[i];
        float dо = deg_out[i];
        float a = 1.0f / sqrtf(fmaxf(di, 1.0f));
        float b = 1.0f / sqrtf(fmaxf(dо, 1.0f));
        isi[i] = a;
        iso[i] = b;
        h0s[i] = di * b;   // h0 = deg_in, pre-scaled by inv_sqrt_out
    }
}

__global__ void conv1_edge_kernel(const int* __restrict__ src, const int* __restrict__ dst,
                                  const float* __restrict__ h0s, float* __restrict__ agg1, int E) {
    int i = blockIdx.x * TB + threadIdx.x;
    if (i < E) {
        atomicAdd(&agg1[dst[i]], h0s[src[i]]);
    }
}

__global__ void node1_kernel(const float* __restrict__ agg1, const float* __restrict__ isi,
                             const float* __restrict__ iso, const float* __restrict__ W1,
                             float* __restrict__ h1s, int N) {
    __shared__ float sW1[8];
    if (threadIdx.x < 8) sW1[threadIdx.x] = W1[threadIdx.x];
    __syncthreads();
    int i = blockIdx.x * TB + threadIdx.x;
    if (i < N) {
        float a = agg1[i] * isi[i];
        float o = iso[i];
        float4 r0, r1;
        r0.x = fmaxf(a * sW1[0], 0.0f) * o;
        r0.y = fmaxf(a * sW1[1], 0.0f) * o;
        r0.z = fmaxf(a * sW1[2], 0.0f) * o;
        r0.w = fmaxf(a * sW1[3], 0.0f) * o;
        r1.x = fmaxf(a * sW1[4], 0.0f) * o;
        r1.y = fmaxf(a * sW1[5], 0.0f) * o;
        r1.z = fmaxf(a * sW1[6], 0.0f) * o;
        r1.w = fmaxf(a * sW1[7], 0.0f) * o;
        float4* out4 = (float4*)(h1s + (size_t)i * 8);
        out4[0] = r0;
        out4[1] = r1;
    }
}

__global__ void conv2_edge_kernel(const int* __restrict__ src, const int* __restrict__ dst,
                                  const float* __restrict__ h1s, float* __restrict__ agg2, int E) {
    int i = blockIdx.x * TB + threadIdx.x;
    if (i < E) {
        int s = src[i];
        int d = dst[i];
        const float4* p = (const float4*)(h1s + (size_t)s * 8);
        float4 a = p[0];
        float4 b = p[1];
        float* q = agg2 + (size_t)d * 8;
        atomicAdd(q + 0, a.x);
        atomicAdd(q + 1, a.y);
        atomicAdd(q + 2, a.z);
        atomicAdd(q + 3, a.w);
        atomicAdd(q + 4, b.x);
        atomicAdd(q + 5, b.y);
        atomicAdd(q + 6, b.z);
        atomicAdd(q + 7, b.w);
    }
}

// node2: h2 = relu((agg2*isi) @ W2); then graph mean-pool accumulation.
// graph_ids is sorted -> almost every wave is graph-uniform; reduce in-wave
// (shfl tree) and issue ONE atomic per wave per feature instead of 64
// same-address atomics per wave.
__global__ void node2_pool_kernel(const float* __restrict__ agg2, const float* __restrict__ isi,
                                  const float* __restrict__ W2, const int* __restrict__ graph_ids,
                                  float* __restrict__ hg, float* __restrict__ counts, int N) {
    __shared__ float sW2[64];
    if (threadIdx.x < 64) sW2[threadIdx.x] = W2[threadIdx.x];
    __syncthreads();

    int i = blockIdx.x * TB + threadIdx.x;
    bool valid = i < N;
    int ii = valid ? i : (N - 1);

    float s = isi[ii];
    const float4* p = (const float4*)(agg2 + (size_t)ii * 8);
    float4 a0 = p[0];
    float4 a1 = p[1];
    float a[8] = { a0.x * s, a0.y * s, a0.z * s, a0.w * s,
                   a1.x * s, a1.y * s, a1.z * s, a1.w * s };

    float vmask = valid ? 1.0f : 0.0f;
    float h[8];
#pragma unroll
    for (int c = 0; c < 8; ++c) {
        float acc = 0.0f;
#pragma unroll
        for (int k = 0; k < 8; ++k) acc += a[k] * sW2[k * 8 + c];
        h[c] = fmaxf(acc, 0.0f) * vmask;
    }

    int g = graph_ids[ii];
    int g0 = __shfl(g, 0, 64);
    bool uniform = __all((!valid) || (g == g0));

    if (uniform) {
        float cnt = vmask;
#pragma unroll
        for (int off = 32; off >= 1; off >>= 1) {
            cnt += __shfl_down(cnt, off, 64);
#pragma unroll
            for (int c = 0; c < 8; ++c) h[c] += __shfl_down(h[c], off, 64);
        }
        if ((threadIdx.x & 63) == 0) {
            atomicAdd(&counts[g0], cnt);
#pragma unroll
            for (int c = 0; c < 8; ++c) atomicAdd(&hg[(size_t)g0 * 8 + c], h[c]);
        }
    } else {
        if (valid) {
            atomicAdd(&counts[g], 1.0f);
#pragma unroll
            for (int c = 0; c < 8; ++c) atomicAdd(&hg[(size_t)g * 8 + c], h[c]);
        }
    }
}

__global__ void final_kernel(const float* __restrict__ hg, const float* __restrict__ counts,
                             const float* __restrict__ Wlast, float* __restrict__ out, int GC) {
    int i = blockIdx.x * TB + threadIdx.x;
    if (i < GC) {
        int g = i >> 3;
        int c = i & 7;
        float inv = 1.0f / fmaxf(counts[g], 1.0f);
        const float* row = hg + (size_t)g * 8;
        float acc = 0.0f;
#pragma unroll
        for (int k = 0; k < 8; ++k) acc += row[k] * Wlast[k * 8 + c];
        out[i] = acc * inv;
    }
}

extern "C" void kernel_launch(void* const* d_in, const int* in_sizes, int n_in,
                              void* d_out, int out_size, void* d_ws, size_t ws_size,
                              hipStream_t stream) {
    const float* W1        = (const float*)d_in[0];
    const float* W2        = (const float*)d_in[1];
    const float* Wlast     = (const float*)d_in[2];
    const int*   src       = (const int*)d_in[3];
    const int*   dst       = (const int*)d_in[4];
    const int*   graph_ids = (const int*)d_in[5];
    float* out = (float*)d_out;

    const int E = in_sizes[3];
    const int N = in_sizes[5];
    const int G = out_size / 8;

    float* ws = (float*)d_ws;

    // Workspace layout (floats); zero-needed buffers first, contiguous.
    size_t off = 0;
    auto alloc = [&](size_t n) { size_t o = off; off += (n + 3) & ~(size_t)3; return o; };
    size_t o_deg_in  = alloc(N);
    size_t o_deg_out = alloc(N);
    size_t o_agg1    = alloc(N);
    size_t o_agg2    = alloc((size_t)N * 8);
    size_t o_hg      = alloc((size_t)G * 8);
    size_t o_counts  = alloc(G);
    size_t zero_floats = off;                 // everything up to here must start at 0
    size_t o_isi     = alloc(N);
    size_t o_iso     = alloc(N);
    size_t o_h0s     = alloc(N);
    size_t o_h1s     = alloc((size_t)N * 8);

    float* deg_in  = ws + o_deg_in;
    float* deg_out = ws + o_deg_out;
    float* agg1    = ws + o_agg1;
    float* agg2    = ws + o_agg2;
    float* hg      = ws + o_hg;
    float* counts  = ws + o_counts;
    float* isi     = ws + o_isi;
    float* iso     = ws + o_iso;
    float* h0s     = ws + o_h0s;
    float* h1s     = ws + o_h1s;

    hipMemsetAsync(ws, 0, zero_floats * sizeof(float), stream);

    int gridE = (E + TB - 1) / TB;
    int gridN = (N + TB - 1) / TB;
    int gridO = (out_size + TB - 1) / TB;

    deg_kernel<<<gridE, TB, 0, stream>>>(src, dst, deg_out, deg_in, E);
    node_prep_kernel<<<gridN, TB, 0, stream>>>(deg_in, deg_out, isi, iso, h0s, N);
    conv1_edge_kernel<<<gridE, TB, 0, stream>>>(src, dst, h0s, agg1, E);
    node1_kernel<<<gridN, TB, 0, stream>>>(agg1, isi, iso, W1, h1s, N);
    conv2_edge_kernel<<<gridE, TB, 0, stream>>>(src, dst, h1s, agg2, E);
    node2_pool_kernel<<<gridN, TB, 0, stream>>>(agg2, isi, W2, graph_ids, hg, counts, N);
    final_kernel<<<gridO, TB, 0, stream>>>(hg, counts, Wlast, out, out_size);
}

// Round 2
// 2080.728 us; speedup vs baseline: 2.7144x; 2.7144x over previous
//
#include <hip/hip_runtime.h>

// GCN algebraically collapsed: since h0 = deg_in >= 0 and all scale factors
// are positive, relu(b*W1) = b*relu(W1) exactly (b>=0), so the whole network
// is rank-1 in the feature dimension:
//   out[g][j] = mean_{i in g}(x_i) * r_j
//   x_i = isi_i * t_i,  t = segsum_dst(s[src]),  s_i = iso_i*isi_i*agg1_i
//   agg1 = segsum_dst(h0s[src]), h0s_i = deg_in_i*iso_i
//   r = relu(relu(W1) @ W2) @ Wlast   (8 values)
// All edge passes are scalar segment-sums via fp32 atomics.

#define TB 256

__global__ void deg_kernel(const int* __restrict__ src, const int* __restrict__ dst,
                           float* __restrict__ deg_out, float* __restrict__ deg_in, int E) {
    int i = blockIdx.x * TB + threadIdx.x;
    int base = i * 4;
    if (base + 3 < E) {
        int4 s4 = ((const int4*)src)[i];
        int4 d4 = ((const int4*)dst)[i];
        atomicAdd(&deg_out[s4.x], 1.0f);
        atomicAdd(&deg_out[s4.y], 1.0f);
        atomicAdd(&deg_out[s4.z], 1.0f);
        atomicAdd(&deg_out[s4.w], 1.0f);
        atomicAdd(&deg_in[d4.x], 1.0f);
        atomicAdd(&deg_in[d4.y], 1.0f);
        atomicAdd(&deg_in[d4.z], 1.0f);
        atomicAdd(&deg_in[d4.w], 1.0f);
    } else {
        for (int j = base; j < E; ++j) {
            atomicAdd(&deg_out[src[j]], 1.0f);
            atomicAdd(&deg_in[dst[j]], 1.0f);
        }
    }
}

__global__ void node_prep_kernel(const float* __restrict__ deg_in, const float* __restrict__ deg_out,
                                 float* __restrict__ isi, float* __restrict__ iso,
                                 float* __restrict__ h0s, int N) {
    int i = blockIdx.x * TB + threadIdx.x;
    if (i < N) {
        float di = deg_in[i];
        float dn = deg_out[i];
        float a = 1.0f / sqrtf(fmaxf(di, 1.0f));
        float b = 1.0f / sqrtf(fmaxf(dn, 1.0f));
        isi[i] = a;
        iso[i] = b;
        h0s[i] = di * b;   // h0 pre-scaled by inv_sqrt_out
    }
}

// scalar segment-sum over dst: t[dst] += vals[src]
__global__ void conv_edge_kernel(const int* __restrict__ src, const int* __restrict__ dst,
                                 const float* __restrict__ vals, float* __restrict__ t, int E) {
    int i = blockIdx.x * TB + threadIdx.x;
    int base = i * 4;
    if (base + 3 < E) {
        int4 s4 = ((const int4*)src)[i];
        int4 d4 = ((const int4*)dst)[i];
        float v0 = vals[s4.x];
        float v1 = vals[s4.y];
        float v2 = vals[s4.z];
        float v3 = vals[s4.w];
        atomicAdd(&t[d4.x], v0);
        atomicAdd(&t[d4.y], v1);
        atomicAdd(&t[d4.z], v2);
        atomicAdd(&t[d4.w], v3);
    } else {
        for (int j = base; j < E; ++j) {
            atomicAdd(&t[dst[j]], vals[src[j]]);
        }
    }
}

// s_i = agg1_i * isi_i * iso_i  (input to conv2's aggregation)
__global__ void node_mid_kernel(const float* __restrict__ agg1, const float* __restrict__ isi,
                                const float* __restrict__ iso, float* __restrict__ s, int N) {
    int i = blockIdx.x * TB + threadIdx.x;
    if (i < N) {
        s[i] = agg1[i] * isi[i] * iso[i];
    }
}

// x_i = t2_i * isi_i; segmented (sorted graph_ids) mean-pool accumulation.
__global__ void pool_kernel(const float* __restrict__ t2, const float* __restrict__ isi,
                            const int* __restrict__ graph_ids,
                            float* __restrict__ Xsum, float* __restrict__ counts, int N) {
    int i = blockIdx.x * TB + threadIdx.x;
    bool valid = i < N;
    int ii = valid ? i : (N - 1);

    float x = valid ? t2[ii] * isi[ii] : 0.0f;
    float cnt = valid ? 1.0f : 0.0f;

    int g = graph_ids[ii];
    int g0 = __shfl(g, 0, 64);
    bool uniform = __all((!valid) || (g == g0));

    if (uniform) {
#pragma unroll
        for (int off = 32; off >= 1; off >>= 1) {
            x += __shfl_down(x, off, 64);
            cnt += __shfl_down(cnt, off, 64);
        }
        if ((threadIdx.x & 63) == 0) {
            atomicAdd(&Xsum[g0], x);
            atomicAdd(&counts[g0], cnt);
        }
    } else {
        if (valid) {
            atomicAdd(&Xsum[g], x);
            atomicAdd(&counts[g], 1.0f);
        }
    }
}

// out[g][j] = (Xsum[g]/max(cnt,1)) * r_j ; r = relu(relu(W1) @ W2) @ Wlast
__global__ void final_kernel(const float* __restrict__ Xsum, const float* __restrict__ counts,
                             const float* __restrict__ W1, const float* __restrict__ W2,
                             const float* __restrict__ Wlast, float* __restrict__ out, int GC) {
    int i = blockIdx.x * TB + threadIdx.x;
    if (i < GC) {
        int g = i >> 3;
        int j = i & 7;
        float r = 0.0f;
#pragma unroll
        for (int c = 0; c < 8; ++c) {
            float m = 0.0f;
#pragma unroll
            for (int k = 0; k < 8; ++k) {
                m += fmaxf(W1[k], 0.0f) * W2[k * 8 + c];
            }
            r += fmaxf(m, 0.0f) * Wlast[c * 8 + j];
        }
        float X = Xsum[g] / fmaxf(counts[g], 1.0f);
        out[i] = X * r;
    }
}

extern "C" void kernel_launch(void* const* d_in, const int* in_sizes, int n_in,
                              void* d_out, int out_size, void* d_ws, size_t ws_size,
                              hipStream_t stream) {
    const float* W1        = (const float*)d_in[0];
    const float* W2        = (const float*)d_in[1];
    const float* Wlast     = (const float*)d_in[2];
    const int*   src       = (const int*)d_in[3];
    const int*   dst       = (const int*)d_in[4];
    const int*   graph_ids = (const int*)d_in[5];
    float* out = (float*)d_out;

    const int E = in_sizes[3];
    const int N = in_sizes[5];
    const int G = out_size / 8;

    float* ws = (float*)d_ws;

    size_t off = 0;
    auto alloc = [&](size_t n) { size_t o = off; off += (n + 3) & ~(size_t)3; return o; };
    size_t o_deg_in  = alloc(N);
    size_t o_deg_out = alloc(N);
    size_t o_agg1    = alloc(N);   // t1
    size_t o_t2      = alloc(N);
    size_t o_Xsum    = alloc(G);
    size_t o_counts  = alloc(G);
    size_t zero_floats = off;      // buffers above must start at 0
    size_t o_isi     = alloc(N);
    size_t o_iso     = alloc(N);
    size_t o_h0s     = alloc(N);
    size_t o_s       = alloc(N);

    float* deg_in  = ws + o_deg_in;
    float* deg_out = ws + o_deg_out;
    float* agg1    = ws + o_agg1;
    float* t2      = ws + o_t2;
    float* Xsum    = ws + o_Xsum;
    float* counts  = ws + o_counts;
    float* isi     = ws + o_isi;
    float* iso     = ws + o_iso;
    float* h0s     = ws + o_h0s;
    float* s       = ws + o_s;

    hipMemsetAsync(ws, 0, zero_floats * sizeof(float), stream);

    int gridE4 = ((E + 3) / 4 + TB - 1) / TB;
    int gridN  = (N + TB - 1) / TB;
    int gridO  = (out_size + TB - 1) / TB;

    deg_kernel<<<gridE4, TB, 0, stream>>>(src, dst, deg_out, deg_in, E);
    node_prep_kernel<<<gridN, TB, 0, stream>>>(deg_in, deg_out, isi, iso, h0s, N);
    conv_edge_kernel<<<gridE4, TB, 0, stream>>>(src, dst, h0s, agg1, E);
    node_mid_kernel<<<gridN, TB, 0, stream>>>(agg1, isi, iso, s, N);
    conv_edge_kernel<<<gridE4, TB, 0, stream>>>(src, dst, s, t2, E);
    pool_kernel<<<gridN, TB, 0, stream>>>(t2, isi, graph_ids, Xsum, counts, N);
    final_kernel<<<gridO, TB, 0, stream>>>(Xsum, counts, W1, W2, Wlast, out, out_size);
}

// Round 3
// 1378.235 us; speedup vs baseline: 4.0979x; 1.5097x over previous
//
#include <hip/hip_runtime.h>

// GCN rank-1 collapse (R2) + per-XCD-replicated local-scope atomics (R3).
//
// Device atomics on MI355X route past the per-XCD L2 (~20 G atomics/s,
// ~32 B fabric traffic each — R2 counters). Fix: replicate counters per XCD
// (replica index = HW_REG_XCC_ID, measured 0..7), update with
// WORKGROUP-scope atomics that execute in the local TCC, reduce replicas in
// the next kernel (kernel-boundary release/acquire guarantees visibility).
// Heavy scatters use integer atomics (degrees = counts; conv1 fixed-point
// x2^17: agg1 <= 4096 -> max 2^29, quantization error ~1e-4 << 0.189 thresh).
// conv2+pool fused into a per-block LDS histogram over G graphs, flushed with
// plain stores and reduced atomic-free; counts via binary search (sorted ids).

#define TB 256
#define NXCD 8
#define HBINS 1024
#define POOL_BLOCKS 1024
#define FXS 131072.0f
#define FXSI (1.0f / 131072.0f)

__device__ __forceinline__ int xcc_id() {
    int x;
    asm volatile("s_getreg_b32 %0, hwreg(HW_REG_XCC_ID)" : "=s"(x));
    return x & (NXCD - 1);
}

__device__ __forceinline__ void wg_add_u32(unsigned* p, unsigned v) {
    __hip_atomic_fetch_add(p, v, __ATOMIC_RELAXED, __HIP_MEMORY_SCOPE_WORKGROUP);
}

// degpack: per-XCD replicas of packed degrees (low16 = deg_out, high16 = deg_in)
__global__ void deg_kernel(const int* __restrict__ src, const int* __restrict__ dst,
                           unsigned* __restrict__ degpack, int N, int E) {
    unsigned* D = degpack + (size_t)xcc_id() * N;
    int i = blockIdx.x * TB + threadIdx.x;
    int base = i * 4;
    if (base + 3 < E) {
        int4 s4 = ((const int4*)src)[i];
        int4 d4 = ((const int4*)dst)[i];
        wg_add_u32(&D[s4.x], 1u);
        wg_add_u32(&D[s4.y], 1u);
        wg_add_u32(&D[s4.z], 1u);
        wg_add_u32(&D[s4.w], 1u);
        wg_add_u32(&D[d4.x], 65536u);
        wg_add_u32(&D[d4.y], 65536u);
        wg_add_u32(&D[d4.z], 65536u);
        wg_add_u32(&D[d4.w], 65536u);
    } else {
        for (int j = base; j < E; ++j) {
            wg_add_u32(&D[src[j]], 1u);
            wg_add_u32(&D[dst[j]], 65536u);
        }
    }
}

__global__ void node_prep_kernel(const unsigned* __restrict__ degpack,
                                 const int* __restrict__ graph_ids,
                                 float* __restrict__ pio, unsigned* __restrict__ h0fx,
                                 float2* __restrict__ z, int N) {
    int i = blockIdx.x * TB + threadIdx.x;
    if (i < N) {
        unsigned p = 0;
#pragma unroll
        for (int r = 0; r < NXCD; ++r) p += degpack[(size_t)r * N + i];
        float dout = (float)(p & 0xFFFFu);
        float din  = (float)(p >> 16);
        float a = 1.0f / sqrtf(fmaxf(din, 1.0f));   // inv_sqrt_in
        float b = 1.0f / sqrtf(fmaxf(dout, 1.0f));  // inv_sqrt_out
        pio[i] = a * b;
        h0fx[i] = __float2uint_rn(din * b * FXS);
        float2 zz;
        zz.x = a;
        zz.y = __int_as_float(graph_ids[i]);
        z[i] = zz;
    }
}

// agg1r[xcc][dst] += h0fx[src]  (fixed-point u32, per-XCD replicas)
__global__ void conv1_kernel(const int* __restrict__ src, const int* __restrict__ dst,
                             const unsigned* __restrict__ h0fx,
                             unsigned* __restrict__ agg1r, int N, int E) {
    unsigned* A = agg1r + (size_t)xcc_id() * N;
    int i = blockIdx.x * TB + threadIdx.x;
    int base = i * 4;
    if (base + 3 < E) {
        int4 s4 = ((const int4*)src)[i];
        int4 d4 = ((const int4*)dst)[i];
        unsigned v0 = h0fx[s4.x];
        unsigned v1 = h0fx[s4.y];
        unsigned v2 = h0fx[s4.z];
        unsigned v3 = h0fx[s4.w];
        wg_add_u32(&A[d4.x], v0);
        wg_add_u32(&A[d4.y], v1);
        wg_add_u32(&A[d4.z], v2);
        wg_add_u32(&A[d4.w], v3);
    } else {
        for (int j = base; j < E; ++j) {
            wg_add_u32(&A[dst[j]], h0fx[src[j]]);
        }
    }
}

// s_i = agg1_i * isi_i * iso_i = (sum of replicas * FXSI) * pio_i
__global__ void node_mid_kernel(const unsigned* __restrict__ agg1r,
                                const float* __restrict__ pio,
                                float* __restrict__ s, int N) {
    int i = blockIdx.x * TB + threadIdx.x;
    if (i < N) {
        unsigned t = 0;
#pragma unroll
        for (int r = 0; r < NXCD; ++r) t += agg1r[(size_t)r * N + i];
        s[i] = (float)t * FXSI * pio[i];
    }
}

// Fused conv2 + graph pool: Bpart[block][g] = sum over this block's edges of
// isi[dst]*s[src] where g = graph_ids[dst]. LDS histogram, plain-store flush.
__global__ void conv2_pool_kernel(const int* __restrict__ src, const int* __restrict__ dst,
                                  const float* __restrict__ s, const float2* __restrict__ z,
                                  float* __restrict__ Bpart, int E4, int E) {
    __shared__ float hist[HBINS];
    for (int b = threadIdx.x; b < HBINS; b += TB) hist[b] = 0.0f;
    __syncthreads();

    for (int i = blockIdx.x * TB + threadIdx.x; i < E4; i += gridDim.x * TB) {
        int base = i * 4;
        if (base + 3 < E) {
            int4 s4 = ((const int4*)src)[i];
            int4 d4 = ((const int4*)dst)[i];
            float v0 = s[s4.x];
            float v1 = s[s4.y];
            float v2 = s[s4.z];
            float v3 = s[s4.w];
            float2 z0 = z[d4.x];
            float2 z1 = z[d4.y];
            float2 z2 = z[d4.z];
            float2 z3 = z[d4.w];
            atomicAdd(&hist[__float_as_int(z0.y)], v0 * z0.x);
            atomicAdd(&hist[__float_as_int(z1.y)], v1 * z1.x);
            atomicAdd(&hist[__float_as_int(z2.y)], v2 * z2.x);
            atomicAdd(&hist[__float_as_int(z3.y)], v3 * z3.x);
        } else {
            for (int j = base; j < E; ++j) {
                float2 zz = z[dst[j]];
                atomicAdd(&hist[__float_as_int(zz.y)], s[src[j]] * zz.x);
            }
        }
    }
    __syncthreads();

    float* row = Bpart + (size_t)blockIdx.x * HBINS;
    for (int b = threadIdx.x; b < HBINS; b += TB) row[b] = hist[b];
}

// One block per graph: reduce POOL_BLOCKS partials, count nodes by binary
// search on sorted graph_ids, apply the rank-1 head r = relu(relu(W1)@W2)@Wlast.
__global__ void final_kernel(const float* __restrict__ Bpart, const int* __restrict__ graph_ids,
                             const float* __restrict__ W1, const float* __restrict__ W2,
                             const float* __restrict__ Wlast, float* __restrict__ out, int N) {
    int g = blockIdx.x;
    float part = 0.0f;
    for (int b = threadIdx.x; b < POOL_BLOCKS; b += TB)
        part += Bpart[(size_t)b * HBINS + g];
#pragma unroll
    for (int off = 32; off >= 1; off >>= 1) part += __shfl_down(part, off, 64);

    __shared__ float red[TB / 64];
    __shared__ float sX, sC;
    if ((threadIdx.x & 63) == 0) red[threadIdx.x >> 6] = part;
    __syncthreads();
    if (threadIdx.x == 0) {
        float X = 0.0f;
#pragma unroll
        for (int w = 0; w < TB / 64; ++w) X += red[w];
        int lo = 0, hi = N;
        while (lo < hi) { int m = (lo + hi) >> 1; if (graph_ids[m] < g) lo = m + 1; else hi = m; }
        int lo2 = lo, hi2 = N;
        while (lo2 < hi2) { int m = (lo2 + hi2) >> 1; if (graph_ids[m] < g + 1) lo2 = m + 1; else hi2 = m; }
        sX = X;
        sC = (float)(lo2 - lo);
    }
    __syncthreads();
    if (threadIdx.x < 8) {
        int j = threadIdx.x;
        float r = 0.0f;
#pragma unroll
        for (int c = 0; c < 8; ++c) {
            float m = 0.0f;
#pragma unroll
            for (int k = 0; k < 8; ++k) m += fmaxf(W1[k], 0.0f) * W2[k * 8 + c];
            r += fmaxf(m, 0.0f) * Wlast[c * 8 + j];
        }
        out[g * 8 + j] = sX / fmaxf(sC, 1.0f) * r;
    }
}

extern "C" void kernel_launch(void* const* d_in, const int* in_sizes, int n_in,
                              void* d_out, int out_size, void* d_ws, size_t ws_size,
                              hipStream_t stream) {
    const float* W1        = (const float*)d_in[0];
    const float* W2        = (const float*)d_in[1];
    const float* Wlast     = (const float*)d_in[2];
    const int*   src       = (const int*)d_in[3];
    const int*   dst       = (const int*)d_in[4];
    const int*   graph_ids = (const int*)d_in[5];
    float* out = (float*)d_out;

    const int E = in_sizes[3];
    const int N = in_sizes[5];
    const int G = out_size / 8;

    float* ws = (float*)d_ws;
    size_t off = 0;
    auto alloc = [&](size_t n) { size_t o = off; off += (n + 3) & ~(size_t)3; return o; };
    size_t o_reps  = alloc((size_t)NXCD * N);        // degpack, then reused as agg1r
    size_t o_pio   = alloc(N);
    size_t o_h0fx  = alloc(N);                        // reused as s after conv1
    size_t o_z     = alloc((size_t)2 * N);
    size_t o_Bpart = alloc((size_t)POOL_BLOCKS * HBINS);

    unsigned* reps  = (unsigned*)(ws + o_reps);
    float*    pio   = ws + o_pio;
    unsigned* h0fx  = (unsigned*)(ws + o_h0fx);
    float*    sbuf  = ws + o_h0fx;                    // alias: s overwrites h0fx
    float2*   z     = (float2*)(ws + o_z);
    float*    Bpart = ws + o_Bpart;

    int E4 = (E + 3) / 4;
    int gridE4 = (E4 + TB - 1) / TB;
    int gridN  = (N + TB - 1) / TB;
    size_t repBytes = (size_t)NXCD * N * sizeof(unsigned);

    hipMemsetAsync(reps, 0, repBytes, stream);
    deg_kernel<<<gridE4, TB, 0, stream>>>(src, dst, reps, N, E);
    node_prep_kernel<<<gridN, TB, 0, stream>>>(reps, graph_ids, pio, h0fx, z, N);
    hipMemsetAsync(reps, 0, repBytes, stream);
    conv1_kernel<<<gridE4, TB, 0, stream>>>(src, dst, h0fx, reps, N, E);
    node_mid_kernel<<<gridN, TB, 0, stream>>>(reps, pio, sbuf, N);
    conv2_pool_kernel<<<POOL_BLOCKS, TB, 0, stream>>>(src, dst, sbuf, z, Bpart, E4, E);
    final_kernel<<<G, TB, 0, stream>>>(Bpart, graph_ids, W1, W2, Wlast, out, N);
}

// Round 4
// 597.660 us; speedup vs baseline: 9.4499x; 2.3061x over previous
//
#include <hip/hip_runtime.h>

// GCN rank-1 collapse + zero-global-atomic bucket-partitioned histograms.
//
// R3 evidence: global atomics on gfx950 execute past L2 at ~27 G/s with 32 B
// fabric traffic each, regardless of memory scope (WRITE_SIZE identical for
// device-scope fp32 and workgroup-scope u32). So all 40M atomics are replaced
// by: partition edges into buckets of 1024 nodes (exact offsets via
// count->scan->scatter, cursors in LDS), then per-bucket LDS histograms with
// coalesced flushes. dst-partition payload packs (localDst<<19)|src in u32.
// Pipeline: count -> row-scan -> bucket-base -> scatter16(src,dst) ->
// hist16(deg) -> prep -> scatter32(dst,src) -> conv1-hist -> pool-hist -> final.
// No global atomics, no memsets (every buffer written before read).

#define TB 256
#define BSH 10
#define BNODES 1024
#define MAXNB 512
#define CHUNK 8192
#define MAXITEMS 8   // supports NCH <= 2048 (E <= 16.7M)

// ======================= fast path kernels =======================

__global__ void count_kernel(const int* __restrict__ src, const int* __restrict__ dst,
                             unsigned* __restrict__ cntS, unsigned* __restrict__ cntD,
                             int NB, int NCH, int E) {
    __shared__ unsigned cs[MAXNB], cd[MAXNB];
    for (int b = threadIdx.x; b < NB; b += TB) { cs[b] = 0u; cd[b] = 0u; }
    __syncthreads();
    int blk = blockIdx.x;
    int q0 = blk * (CHUNK / 4);
    int Eq = E >> 2;
    for (int it = 0; it < CHUNK / 4 / TB; ++it) {
        int q = q0 + it * TB + threadIdx.x;
        if (q < Eq) {
            int4 s4 = ((const int4*)src)[q];
            int4 d4 = ((const int4*)dst)[q];
            atomicAdd(&cs[s4.x >> BSH], 1u);
            atomicAdd(&cs[s4.y >> BSH], 1u);
            atomicAdd(&cs[s4.z >> BSH], 1u);
            atomicAdd(&cs[s4.w >> BSH], 1u);
            atomicAdd(&cd[d4.x >> BSH], 1u);
            atomicAdd(&cd[d4.y >> BSH], 1u);
            atomicAdd(&cd[d4.z >> BSH], 1u);
            atomicAdd(&cd[d4.w >> BSH], 1u);
        }
    }
    if (blk == gridDim.x - 1) {
        for (int j = (Eq << 2) + threadIdx.x; j < E; j += TB) {
            atomicAdd(&cs[src[j] >> BSH], 1u);
            atomicAdd(&cd[dst[j] >> BSH], 1u);
        }
    }
    __syncthreads();
    for (int b = threadIdx.x; b < NB; b += TB) {
        cntS[(size_t)b * NCH + blk] = cs[b];
        cntD[(size_t)b * NCH + blk] = cd[b];
    }
}

// Per-bucket row: exclusive prefix over chunk-blocks, in place; row total out.
__global__ void scan_kernel(unsigned* __restrict__ cntD, unsigned* __restrict__ cntS,
                            unsigned* __restrict__ totD, unsigned* __restrict__ totS,
                            int NB, int NCH, int ITEMS) {
    int bi = blockIdx.x;
    unsigned* row;
    unsigned* tot;
    int b;
    if (bi < NB) { b = bi; row = cntD + (size_t)b * NCH; tot = totD; }
    else         { b = bi - NB; row = cntS + (size_t)b * NCH; tot = totS; }
    unsigned v[MAXITEMS];
    unsigned sum = 0;
    int base = threadIdx.x * ITEMS;
    for (int k = 0; k < ITEMS; ++k) {
        int idx = base + k;
        unsigned x = (idx < NCH) ? row[idx] : 0u;
        v[k] = x;
        sum += x;
    }
    __shared__ unsigned wsum[TB];
    wsum[threadIdx.x] = sum;
    __syncthreads();
    if (threadIdx.x == 0) {
        unsigned carry = 0;
        for (int i = 0; i < TB; ++i) { unsigned t = wsum[i]; wsum[i] = carry; carry += t; }
        tot[b] = carry;
    }
    __syncthreads();
    unsigned run = wsum[threadIdx.x];
    for (int k = 0; k < ITEMS; ++k) {
        int idx = base + k;
        if (idx < NCH) { unsigned old = v[k]; row[idx] = run; run += old; }
    }
}

__global__ void base_kernel(const unsigned* __restrict__ totD, const unsigned* __restrict__ totS,
                            unsigned* __restrict__ baseD, unsigned* __restrict__ baseS, int NB) {
    if (threadIdx.x == 0 && blockIdx.x == 0) {
        unsigned c = 0;
        for (int b = 0; b < NB; ++b) { baseD[b] = c; c += totD[b]; }
        c = 0;
        for (int b = 0; b < NB; ++b) { baseS[b] = c; c += totS[b]; }
    }
}

__global__ void scatter16_kernel(const int* __restrict__ src, const int* __restrict__ dst,
                                 const unsigned* __restrict__ cntS, const unsigned* __restrict__ cntD,
                                 const unsigned* __restrict__ baseS, const unsigned* __restrict__ baseD,
                                 unsigned short* __restrict__ srcP, unsigned short* __restrict__ dstP,
                                 int NB, int NCH, int E) {
    __shared__ unsigned so[MAXNB], dof[MAXNB];
    int blk = blockIdx.x;
    for (int b = threadIdx.x; b < NB; b += TB) {
        so[b]  = baseS[b] + cntS[(size_t)b * NCH + blk];
        dof[b] = baseD[b] + cntD[(size_t)b * NCH + blk];
    }
    __syncthreads();
    int q0 = blk * (CHUNK / 4);
    int Eq = E >> 2;
    for (int it = 0; it < CHUNK / 4 / TB; ++it) {
        int q = q0 + it * TB + threadIdx.x;
        if (q < Eq) {
            int4 s4 = ((const int4*)src)[q];
            int4 d4 = ((const int4*)dst)[q];
            unsigned p;
            p = atomicAdd(&so[s4.x >> BSH], 1u); srcP[p] = (unsigned short)(s4.x & (BNODES - 1));
            p = atomicAdd(&so[s4.y >> BSH], 1u); srcP[p] = (unsigned short)(s4.y & (BNODES - 1));
            p = atomicAdd(&so[s4.z >> BSH], 1u); srcP[p] = (unsigned short)(s4.z & (BNODES - 1));
            p = atomicAdd(&so[s4.w >> BSH], 1u); srcP[p] = (unsigned short)(s4.w & (BNODES - 1));
            p = atomicAdd(&dof[d4.x >> BSH], 1u); dstP[p] = (unsigned short)(d4.x & (BNODES - 1));
            p = atomicAdd(&dof[d4.y >> BSH], 1u); dstP[p] = (unsigned short)(d4.y & (BNODES - 1));
            p = atomicAdd(&dof[d4.z >> BSH], 1u); dstP[p] = (unsigned short)(d4.z & (BNODES - 1));
            p = atomicAdd(&dof[d4.w >> BSH], 1u); dstP[p] = (unsigned short)(d4.w & (BNODES - 1));
        }
    }
    if (blk == gridDim.x - 1) {
        for (int j = (Eq << 2) + threadIdx.x; j < E; j += TB) {
            int s = src[j], d = dst[j];
            unsigned p;
            p = atomicAdd(&so[s >> BSH], 1u);  srcP[p] = (unsigned short)(s & (BNODES - 1));
            p = atomicAdd(&dof[d >> BSH], 1u); dstP[p] = (unsigned short)(d & (BNODES - 1));
        }
    }
}

__global__ void hist16_kernel(const unsigned short* __restrict__ srcP, const unsigned short* __restrict__ dstP,
                              const unsigned* __restrict__ baseS, const unsigned* __restrict__ baseD,
                              const unsigned* __restrict__ totS, const unsigned* __restrict__ totD,
                              float* __restrict__ deg_out, float* __restrict__ deg_in, int NB) {
    __shared__ unsigned hist[BNODES];
    for (int t = threadIdx.x; t < BNODES; t += TB) hist[t] = 0u;
    __syncthreads();
    int bi = blockIdx.x;
    const unsigned short* part;
    unsigned start, cnt;
    float* out;
    int b;
    if (bi < NB) { b = bi; part = dstP; start = baseD[b]; cnt = totD[b]; out = deg_in; }
    else         { b = bi - NB; part = srcP; start = baseS[b]; cnt = totS[b]; out = deg_out; }
    for (unsigned i = threadIdx.x; i < cnt; i += TB)
        atomicAdd(&hist[part[start + i]], 1u);
    __syncthreads();
    int nbase = b << BSH;
    for (int t = threadIdx.x; t < BNODES; t += TB)
        out[nbase + t] = (float)hist[t];
}

__global__ void prep_kernel(const float* __restrict__ deg_in, const float* __restrict__ deg_out,
                            float* __restrict__ pio, float* __restrict__ h0s,
                            float* __restrict__ isiA, int N, int Npad) {
    int i = blockIdx.x * TB + threadIdx.x;
    if (i < Npad) {
        if (i < N) {
            float din = deg_in[i], dout = deg_out[i];
            float a  = 1.0f / sqrtf(fmaxf(din, 1.0f));   // inv_sqrt_in
            float bo = 1.0f / sqrtf(fmaxf(dout, 1.0f));  // inv_sqrt_out
            pio[i] = a * bo;
            h0s[i] = din * bo;
            isiA[i] = a;
        } else {
            pio[i] = 0.0f; h0s[i] = 0.0f; isiA[i] = 0.0f;
        }
    }
}

__global__ void scatter32_kernel(const int* __restrict__ src, const int* __restrict__ dst,
                                 const unsigned* __restrict__ cntD, const unsigned* __restrict__ baseD,
                                 unsigned* __restrict__ dstP32, int NB, int NCH, int E) {
    __shared__ unsigned dof[MAXNB];
    int blk = blockIdx.x;
    for (int b = threadIdx.x; b < NB; b += TB)
        dof[b] = baseD[b] + cntD[(size_t)b * NCH + blk];
    __syncthreads();
    int q0 = blk * (CHUNK / 4);
    int Eq = E >> 2;
    for (int it = 0; it < CHUNK / 4 / TB; ++it) {
        int q = q0 + it * TB + threadIdx.x;
        if (q < Eq) {
            int4 s4 = ((const int4*)src)[q];
            int4 d4 = ((const int4*)dst)[q];
            unsigned p;
            p = atomicAdd(&dof[d4.x >> BSH], 1u); dstP32[p] = ((unsigned)(d4.x & (BNODES - 1)) << 19) | (unsigned)s4.x;
            p = atomicAdd(&dof[d4.y >> BSH], 1u); dstP32[p] = ((unsigned)(d4.y & (BNODES - 1)) << 19) | (unsigned)s4.y;
            p = atomicAdd(&dof[d4.z >> BSH], 1u); dstP32[p] = ((unsigned)(d4.z & (BNODES - 1)) << 19) | (unsigned)s4.z;
            p = atomicAdd(&dof[d4.w >> BSH], 1u); dstP32[p] = ((unsigned)(d4.w & (BNODES - 1)) << 19) | (unsigned)s4.w;
        }
    }
    if (blk == gridDim.x - 1) {
        for (int j = (Eq << 2) + threadIdx.x; j < E; j += TB) {
            int s = src[j], d = dst[j];
            unsigned p = atomicAdd(&dof[d >> BSH], 1u);
            dstP32[p] = ((unsigned)(d & (BNODES - 1)) << 19) | (unsigned)s;
        }
    }
}

__global__ void conv1h_kernel(const unsigned* __restrict__ dstP32,
                              const unsigned* __restrict__ baseD, const unsigned* __restrict__ totD,
                              const float* __restrict__ h0s, const float* __restrict__ pio,
                              float* __restrict__ sarr, int NB) {
    __shared__ float hist[BNODES];
    for (int t = threadIdx.x; t < BNODES; t += TB) hist[t] = 0.0f;
    __syncthreads();
    int b = blockIdx.x;
    unsigned start = baseD[b], cnt = totD[b];
    for (unsigned i = threadIdx.x; i < cnt; i += TB) {
        unsigned e = dstP32[start + i];
        atomicAdd(&hist[e >> 19], h0s[e & 0x7FFFFu]);
    }
    __syncthreads();
    int nbase = b << BSH;
    for (int t = threadIdx.x; t < BNODES; t += TB)
        sarr[nbase + t] = hist[t] * pio[nbase + t];
}

__global__ void poolh_kernel(const unsigned* __restrict__ dstP32,
                             const unsigned* __restrict__ baseD, const unsigned* __restrict__ totD,
                             const float* __restrict__ sarr, const float* __restrict__ isiA,
                             const int* __restrict__ graph_ids,
                             float* __restrict__ Bpart, int NB, int N, int G) {
    __shared__ float histg[1024];
    __shared__ float isiL[BNODES];
    __shared__ int gidL[BNODES];
    for (int t = threadIdx.x; t < G; t += TB) histg[t] = 0.0f;
    int b = blockIdx.x;
    int nbase = b << BSH;
    for (int t = threadIdx.x; t < BNODES; t += TB) {
        int node = nbase + t;
        isiL[t] = (node < N) ? isiA[node] : 0.0f;
        gidL[t] = (node < N) ? graph_ids[node] : 0;
    }
    __syncthreads();
    unsigned start = baseD[b], cnt = totD[b];
    for (unsigned i = threadIdx.x; i < cnt; i += TB) {
        unsigned e = dstP32[start + i];
        unsigned l = e >> 19;
        atomicAdd(&histg[gidL[l]], sarr[e & 0x7FFFFu] * isiL[l]);
    }
    __syncthreads();
    float* row = Bpart + (size_t)b * G;
    for (int t = threadIdx.x; t < G; t += TB) row[t] = histg[t];
}

__global__ void final2_kernel(const float* __restrict__ Bpart, const int* __restrict__ graph_ids,
                              const float* __restrict__ W1, const float* __restrict__ W2,
                              const float* __restrict__ Wlast,
                              float* __restrict__ out, int NB, int N, int G) {
    int g = blockIdx.x;
    float part = 0.0f;
    for (int p = threadIdx.x; p < NB; p += TB) part += Bpart[(size_t)p * G + g];
#pragma unroll
    for (int off = 32; off >= 1; off >>= 1) part += __shfl_down(part, off, 64);

    __shared__ float red[TB / 64];
    __shared__ float sX, sC;
    if ((threadIdx.x & 63) == 0) red[threadIdx.x >> 6] = part;
    __syncthreads();
    if (threadIdx.x == 0) {
        float X = 0.0f;
#pragma unroll
        for (int w = 0; w < TB / 64; ++w) X += red[w];
        int lo = 0, hi = N;
        while (lo < hi) { int m = (lo + hi) >> 1; if (graph_ids[m] < g) lo = m + 1; else hi = m; }
        int lo2 = lo, hi2 = N;
        while (lo2 < hi2) { int m = (lo2 + hi2) >> 1; if (graph_ids[m] < g + 1) lo2 = m + 1; else hi2 = m; }
        sX = X;
        sC = (float)(lo2 - lo);
    }
    __syncthreads();
    if (threadIdx.x < 8) {
        int j = threadIdx.x;
        float r = 0.0f;
#pragma unroll
        for (int c = 0; c < 8; ++c) {
            float m = 0.0f;
#pragma unroll
            for (int k = 0; k < 8; ++k) m += fmaxf(W1[k], 0.0f) * W2[k * 8 + c];
            r += fmaxf(m, 0.0f) * Wlast[c * 8 + j];
        }
        out[g * 8 + j] = sX / fmaxf(sC, 1.0f) * r;
    }
}

// ======================= fallback (atomic) path =======================

__global__ void fb_deg_kernel(const int* __restrict__ src, const int* __restrict__ dst,
                              float* __restrict__ deg_out, float* __restrict__ deg_in, int E) {
    int i = blockIdx.x * TB + threadIdx.x;
    if (i < E) {
        atomicAdd(&deg_out[src[i]], 1.0f);
        atomicAdd(&deg_in[dst[i]], 1.0f);
    }
}

__global__ void fb_prep_kernel(const float* __restrict__ deg_in, const float* __restrict__ deg_out,
                               float* __restrict__ isi, float* __restrict__ iso,
                               float* __restrict__ h0s, int N) {
    int i = blockIdx.x * TB + threadIdx.x;
    if (i < N) {
        float di = deg_in[i], dn = deg_out[i];
        float a = 1.0f / sqrtf(fmaxf(di, 1.0f));
        float b = 1.0f / sqrtf(fmaxf(dn, 1.0f));
        isi[i] = a; iso[i] = b; h0s[i] = di * b;
    }
}

__global__ void fb_conv_kernel(const int* __restrict__ src, const int* __restrict__ dst,
                               const float* __restrict__ vals, float* __restrict__ t, int E) {
    int i = blockIdx.x * TB + threadIdx.x;
    if (i < E) atomicAdd(&t[dst[i]], vals[src[i]]);
}

__global__ void fb_mid_kernel(const float* __restrict__ agg1, const float* __restrict__ isi,
                              const float* __restrict__ iso, float* __restrict__ s, int N) {
    int i = blockIdx.x * TB + threadIdx.x;
    if (i < N) s[i] = agg1[i] * isi[i] * iso[i];
}

__global__ void fb_pool_kernel(const float* __restrict__ t2, const float* __restrict__ isi,
                               const int* __restrict__ graph_ids,
                               float* __restrict__ Xsum, float* __restrict__ counts, int N) {
    int i = blockIdx.x * TB + threadIdx.x;
    bool valid = i < N;
    int ii = valid ? i : (N - 1);
    float x = valid ? t2[ii] * isi[ii] : 0.0f;
    float cnt = valid ? 1.0f : 0.0f;
    int g = graph_ids[ii];
    int g0 = __shfl(g, 0, 64);
    bool uniform = __all((!valid) || (g == g0));
    if (uniform) {
#pragma unroll
        for (int off = 32; off >= 1; off >>= 1) {
            x += __shfl_down(x, off, 64);
            cnt += __shfl_down(cnt, off, 64);
        }
        if ((threadIdx.x & 63) == 0) { atomicAdd(&Xsum[g0], x); atomicAdd(&counts[g0], cnt); }
    } else if (valid) {
        atomicAdd(&Xsum[g], x); atomicAdd(&counts[g], 1.0f);
    }
}

__global__ void fb_final_kernel(const float* __restrict__ Xsum, const float* __restrict__ counts,
                                const float* __restrict__ W1, const float* __restrict__ W2,
                                const float* __restrict__ Wlast, float* __restrict__ out, int GC) {
    int i = blockIdx.x * TB + threadIdx.x;
    if (i < GC) {
        int g = i >> 3, j = i & 7;
        float r = 0.0f;
#pragma unroll
        for (int c = 0; c < 8; ++c) {
            float m = 0.0f;
#pragma unroll
            for (int k = 0; k < 8; ++k) m += fmaxf(W1[k], 0.0f) * W2[k * 8 + c];
            r += fmaxf(m, 0.0f) * Wlast[c * 8 + j];
        }
        out[i] = Xsum[g] / fmaxf(counts[g], 1.0f) * r;
    }
}

// ======================= launch =======================

extern "C" void kernel_launch(void* const* d_in, const int* in_sizes, int n_in,
                              void* d_out, int out_size, void* d_ws, size_t ws_size,
                              hipStream_t stream) {
    const float* W1        = (const float*)d_in[0];
    const float* W2        = (const float*)d_in[1];
    const float* Wlast     = (const float*)d_in[2];
    const int*   src       = (const int*)d_in[3];
    const int*   dst       = (const int*)d_in[4];
    const int*   graph_ids = (const int*)d_in[5];
    float* out = (float*)d_out;

    const int E = in_sizes[3];
    const int N = in_sizes[5];
    const int G = out_size / 8;

    int NB    = (N + BNODES - 1) >> BSH;
    int Npad  = NB << BSH;
    int NCH   = (E + CHUNK - 1) / CHUNK;
    int ITEMS = (NCH + TB - 1) / TB;

    char* base = (char*)d_ws;
    size_t off = 0;
    auto A = [&](size_t bytes) { size_t o = off; off = (off + bytes + 15) & ~(size_t)15; return o; };

    size_t o_region = A((size_t)E * 4);
    size_t o_cntD   = A((size_t)NB * NCH * 4);
    size_t o_cntS   = A((size_t)NB * NCH * 4);
    size_t o_totD   = A((size_t)NB * 4);
    size_t o_totS   = A((size_t)NB * 4);
    size_t o_baseD  = A((size_t)NB * 4);
    size_t o_baseS  = A((size_t)NB * 4);
    size_t o_degin  = A((size_t)Npad * 4);
    size_t o_degout = A((size_t)Npad * 4);
    size_t o_pio    = A((size_t)Npad * 4);
    size_t o_h0s    = A((size_t)Npad * 4);
    size_t o_isi    = A((size_t)Npad * 4);
    size_t o_s      = A((size_t)Npad * 4);
    size_t o_Bpart  = A((size_t)NB * G * 4);
    size_t req = off;

    bool fast = (N <= (1 << 19)) && (G <= 1024) && (NB <= MAXNB) &&
                (ITEMS <= MAXITEMS) && (ws_size >= req) && (E >= 4);

    if (fast) {
        unsigned short* srcP16 = (unsigned short*)(base + o_region);
        unsigned short* dstP16 = srcP16 + E;
        unsigned*       dstP32 = (unsigned*)(base + o_region);
        unsigned* cntD  = (unsigned*)(base + o_cntD);
        unsigned* cntS  = (unsigned*)(base + o_cntS);
        unsigned* totD  = (unsigned*)(base + o_totD);
        unsigned* totS  = (unsigned*)(base + o_totS);
        unsigned* baseD = (unsigned*)(base + o_baseD);
        unsigned* baseS = (unsigned*)(base + o_baseS);
        float* deg_in  = (float*)(base + o_degin);
        float* deg_out = (float*)(base + o_degout);
        float* pio     = (float*)(base + o_pio);
        float* h0s     = (float*)(base + o_h0s);
        float* isiA    = (float*)(base + o_isi);
        float* sarr    = (float*)(base + o_s);
        float* Bpart   = (float*)(base + o_Bpart);

        int gridNp = (Npad + TB - 1) / TB;

        count_kernel<<<NCH, TB, 0, stream>>>(src, dst, cntS, cntD, NB, NCH, E);
        scan_kernel<<<2 * NB, TB, 0, stream>>>(cntD, cntS, totD, totS, NB, NCH, ITEMS);
        base_kernel<<<1, 64, 0, stream>>>(totD, totS, baseD, baseS, NB);
        scatter16_kernel<<<NCH, TB, 0, stream>>>(src, dst, cntS, cntD, baseS, baseD,
                                                 srcP16, dstP16, NB, NCH, E);
        hist16_kernel<<<2 * NB, TB, 0, stream>>>(srcP16, dstP16, baseS, baseD, totS, totD,
                                                 deg_out, deg_in, NB);
        prep_kernel<<<gridNp, TB, 0, stream>>>(deg_in, deg_out, pio, h0s, isiA, N, Npad);
        scatter32_kernel<<<NCH, TB, 0, stream>>>(src, dst, cntD, baseD, dstP32, NB, NCH, E);
        conv1h_kernel<<<NB, TB, 0, stream>>>(dstP32, baseD, totD, h0s, pio, sarr, NB);
        poolh_kernel<<<NB, TB, 0, stream>>>(dstP32, baseD, totD, sarr, isiA, graph_ids,
                                            Bpart, NB, N, G);
        final2_kernel<<<G, TB, 0, stream>>>(Bpart, graph_ids, W1, W2, Wlast, out, NB, N, G);
    } else {
        // Compact atomic fallback (R2 structure), ~16 MB of ws.
        float* ws = (float*)d_ws;
        size_t f = 0;
        auto FA = [&](size_t n) { size_t o = f; f += (n + 3) & ~(size_t)3; return o; };
        size_t f_degin  = FA(N);
        size_t f_degout = FA(N);
        size_t f_agg1   = FA(N);
        size_t f_t2     = FA(N);
        size_t f_Xsum   = FA(G);
        size_t f_cnt    = FA(G);
        size_t zf = f;
        size_t f_isi = FA(N);
        size_t f_iso = FA(N);
        size_t f_h0s = FA(N);
        size_t f_s   = FA(N);
        (void)f_s;
        hipMemsetAsync(ws, 0, zf * sizeof(float), stream);
        int gridE = (E + TB - 1) / TB;
        int gridN = (N + TB - 1) / TB;
        int gridO = (out_size + TB - 1) / TB;
        fb_deg_kernel<<<gridE, TB, 0, stream>>>(src, dst, ws + f_degout, ws + f_degin, E);
        fb_prep_kernel<<<gridN, TB, 0, stream>>>(ws + f_degin, ws + f_degout,
                                                 ws + f_isi, ws + f_iso, ws + f_h0s, N);
        fb_conv_kernel<<<gridE, TB, 0, stream>>>(src, dst, ws + f_h0s, ws + f_agg1, E);
        fb_mid_kernel<<<gridN, TB, 0, stream>>>(ws + f_agg1, ws + f_isi, ws + f_iso, ws + f_s, N);
        fb_conv_kernel<<<gridE, TB, 0, stream>>>(src, dst, ws + f_s, ws + f_t2, E);
        fb_pool_kernel<<<gridN, TB, 0, stream>>>(ws + f_t2, ws + f_isi, graph_ids,
                                                 ws + f_Xsum, ws + f_cnt, N);
        fb_final_kernel<<<gridO, TB, 0, stream>>>(ws + f_Xsum, ws + f_cnt, W1, W2, Wlast,
                                                  out, out_size);
    }
}

// Round 5
// 550.650 us; speedup vs baseline: 10.2567x; 1.0854x over previous
//
#include <hip/hip_runtime.h>

// GCN rank-1 collapse + zero-global-atomic bucket partition (R5).
// R4 post-mortem: scatter WRITE_SIZE was 10x payload because per-bucket
// per-chunk ranges (~34 B at CHUNK=8192) were sub-cache-line -> cross-XCD
// partial-line RMW thrash. R5: CHUNK=32768 (ranges ~134-268 B), single fused
// scatter pass (srcP16 + dstP32), deg-hist+prep fused per bucket, pool reduced
// per-bucket in LDS (sorted graph_ids -> ~3 graphs/bucket -> ~1500 atomics).

#define TB 256
#define BSH 10
#define BNODES 1024
#define MAXNB 512
#define CHUNK 32768
#define QPB (CHUNK / 4 / TB)
#define MAXITEMS 8   // NCH <= 2048 -> E <= 67M

// ======================= fast path =======================

__global__ void count_kernel(const int* __restrict__ src, const int* __restrict__ dst,
                             unsigned* __restrict__ cntS, unsigned* __restrict__ cntD,
                             int NB, int NCH, int E) {
    __shared__ unsigned cs[MAXNB], cd[MAXNB];
    for (int b = threadIdx.x; b < NB; b += TB) { cs[b] = 0u; cd[b] = 0u; }
    __syncthreads();
    int blk = blockIdx.x;
    int q0 = blk * (CHUNK / 4);
    int Eq = E >> 2;
#pragma unroll 4
    for (int it = 0; it < QPB; ++it) {
        int q = q0 + it * TB + threadIdx.x;
        if (q < Eq) {
            int4 s4 = ((const int4*)src)[q];
            int4 d4 = ((const int4*)dst)[q];
            atomicAdd(&cs[s4.x >> BSH], 1u);
            atomicAdd(&cs[s4.y >> BSH], 1u);
            atomicAdd(&cs[s4.z >> BSH], 1u);
            atomicAdd(&cs[s4.w >> BSH], 1u);
            atomicAdd(&cd[d4.x >> BSH], 1u);
            atomicAdd(&cd[d4.y >> BSH], 1u);
            atomicAdd(&cd[d4.z >> BSH], 1u);
            atomicAdd(&cd[d4.w >> BSH], 1u);
        }
    }
    if (blk == gridDim.x - 1) {
        for (int j = (Eq << 2) + threadIdx.x; j < E; j += TB) {
            atomicAdd(&cs[src[j] >> BSH], 1u);
            atomicAdd(&cd[dst[j] >> BSH], 1u);
        }
    }
    __syncthreads();
    for (int b = threadIdx.x; b < NB; b += TB) {
        cntS[(size_t)b * NCH + blk] = cs[b];
        cntD[(size_t)b * NCH + blk] = cd[b];
    }
}

__global__ void scan_kernel(unsigned* __restrict__ cntD, unsigned* __restrict__ cntS,
                            unsigned* __restrict__ totD, unsigned* __restrict__ totS,
                            int NB, int NCH, int ITEMS) {
    int bi = blockIdx.x;
    unsigned* row;
    unsigned* tot;
    int b;
    if (bi < NB) { b = bi; row = cntD + (size_t)b * NCH; tot = totD; }
    else         { b = bi - NB; row = cntS + (size_t)b * NCH; tot = totS; }
    unsigned v[MAXITEMS];
    unsigned sum = 0;
    int base = threadIdx.x * ITEMS;
    for (int k = 0; k < ITEMS; ++k) {
        int idx = base + k;
        unsigned x = (idx < NCH) ? row[idx] : 0u;
        v[k] = x;
        sum += x;
    }
    __shared__ unsigned wsum[TB];
    wsum[threadIdx.x] = sum;
    __syncthreads();
    if (threadIdx.x == 0) {
        unsigned carry = 0;
        for (int i = 0; i < TB; ++i) { unsigned t = wsum[i]; wsum[i] = carry; carry += t; }
        tot[b] = carry;
    }
    __syncthreads();
    unsigned run = wsum[threadIdx.x];
    for (int k = 0; k < ITEMS; ++k) {
        int idx = base + k;
        if (idx < NCH) { unsigned old = v[k]; row[idx] = run; run += old; }
    }
}

__global__ void base_kernel(const unsigned* __restrict__ totD, const unsigned* __restrict__ totS,
                            unsigned* __restrict__ baseD, unsigned* __restrict__ baseS, int NB) {
    if (threadIdx.x == 0 && blockIdx.x == 0) {
        unsigned c = 0;
        for (int b = 0; b < NB; ++b) { baseD[b] = c; c += totD[b]; }
        c = 0;
        for (int b = 0; b < NB; ++b) { baseS[b] = c; c += totS[b]; }
    }
}

// One pass: src -> u16 bucket partition, dst -> u32 (localDst<<19)|src partition.
__global__ void scatter_both_kernel(const int* __restrict__ src, const int* __restrict__ dst,
                                    const unsigned* __restrict__ cntS, const unsigned* __restrict__ cntD,
                                    const unsigned* __restrict__ baseS, const unsigned* __restrict__ baseD,
                                    unsigned short* __restrict__ srcP, unsigned* __restrict__ dstP,
                                    int NB, int NCH, int E) {
    __shared__ unsigned so[MAXNB], dof[MAXNB];
    int blk = blockIdx.x;
    for (int b = threadIdx.x; b < NB; b += TB) {
        so[b]  = baseS[b] + cntS[(size_t)b * NCH + blk];
        dof[b] = baseD[b] + cntD[(size_t)b * NCH + blk];
    }
    __syncthreads();
    int q0 = blk * (CHUNK / 4);
    int Eq = E >> 2;
    for (int it = 0; it < QPB; ++it) {
        int q = q0 + it * TB + threadIdx.x;
        if (q < Eq) {
            int4 s4 = ((const int4*)src)[q];
            int4 d4 = ((const int4*)dst)[q];
            unsigned p;
            p = atomicAdd(&so[s4.x >> BSH], 1u);  srcP[p] = (unsigned short)(s4.x & (BNODES - 1));
            p = atomicAdd(&so[s4.y >> BSH], 1u);  srcP[p] = (unsigned short)(s4.y & (BNODES - 1));
            p = atomicAdd(&so[s4.z >> BSH], 1u);  srcP[p] = (unsigned short)(s4.z & (BNODES - 1));
            p = atomicAdd(&so[s4.w >> BSH], 1u);  srcP[p] = (unsigned short)(s4.w & (BNODES - 1));
            p = atomicAdd(&dof[d4.x >> BSH], 1u); dstP[p] = ((unsigned)(d4.x & (BNODES - 1)) << 19) | (unsigned)s4.x;
            p = atomicAdd(&dof[d4.y >> BSH], 1u); dstP[p] = ((unsigned)(d4.y & (BNODES - 1)) << 19) | (unsigned)s4.y;
            p = atomicAdd(&dof[d4.z >> BSH], 1u); dstP[p] = ((unsigned)(d4.z & (BNODES - 1)) << 19) | (unsigned)s4.z;
            p = atomicAdd(&dof[d4.w >> BSH], 1u); dstP[p] = ((unsigned)(d4.w & (BNODES - 1)) << 19) | (unsigned)s4.w;
        }
    }
    if (blk == gridDim.x - 1) {
        for (int j = (Eq << 2) + threadIdx.x; j < E; j += TB) {
            int s = src[j], d = dst[j];
            unsigned p;
            p = atomicAdd(&so[s >> BSH], 1u);  srcP[p] = (unsigned short)(s & (BNODES - 1));
            p = atomicAdd(&dof[d >> BSH], 1u); dstP[p] = ((unsigned)(d & (BNODES - 1)) << 19) | (unsigned)s;
        }
    }
}

// Per bucket: deg_in hist (from dstP), deg_out hist (from srcP), then prep:
// pio = isi*iso, h0s = deg_in*iso, isiA = isi. Deg arrays never hit HBM.
__global__ void degprep_kernel(const unsigned short* __restrict__ srcP, const unsigned* __restrict__ dstP,
                               const unsigned* __restrict__ baseS, const unsigned* __restrict__ baseD,
                               const unsigned* __restrict__ totS, const unsigned* __restrict__ totD,
                               float* __restrict__ pio, float* __restrict__ h0s,
                               float* __restrict__ isiA, int N) {
    __shared__ unsigned hin[BNODES], hout[BNODES];
    for (int t = threadIdx.x; t < BNODES; t += TB) { hin[t] = 0u; hout[t] = 0u; }
    __syncthreads();
    int b = blockIdx.x;
    unsigned sD = baseD[b], cD = totD[b];
    for (unsigned i = threadIdx.x; i < cD; i += TB)
        atomicAdd(&hin[dstP[sD + i] >> 19], 1u);
    unsigned sS = baseS[b], cS = totS[b];
    for (unsigned i = threadIdx.x; i < cS; i += TB)
        atomicAdd(&hout[srcP[sS + i]], 1u);
    __syncthreads();
    int nbase = b << BSH;
    for (int t = threadIdx.x; t < BNODES; t += TB) {
        int node = nbase + t;
        float din  = (float)hin[t];
        float dout = (float)hout[t];
        float a  = 1.0f / sqrtf(fmaxf(din, 1.0f));
        float bo = 1.0f / sqrtf(fmaxf(dout, 1.0f));
        bool ok = node < N;
        pio[node]  = ok ? a * bo : 0.0f;
        h0s[node]  = ok ? din * bo : 0.0f;
        isiA[node] = ok ? a : 0.0f;
    }
}

__global__ void conv1h_kernel(const unsigned* __restrict__ dstP,
                              const unsigned* __restrict__ baseD, const unsigned* __restrict__ totD,
                              const float* __restrict__ h0s, const float* __restrict__ pio,
                              float* __restrict__ sarr, int NB) {
    __shared__ float hist[BNODES];
    for (int t = threadIdx.x; t < BNODES; t += TB) hist[t] = 0.0f;
    __syncthreads();
    int b = blockIdx.x;
    unsigned start = baseD[b], cnt = totD[b];
    for (unsigned i = threadIdx.x; i < cnt; i += TB) {
        unsigned e = dstP[start + i];
        atomicAdd(&hist[e >> 19], h0s[e & 0x7FFFFu]);
    }
    __syncthreads();
    int nbase = b << BSH;
    for (int t = threadIdx.x; t < BNODES; t += TB)
        sarr[nbase + t] = hist[t] * pio[nbase + t];
}

// conv2 aggregate + pool: t2 hist in LDS, then x = t2*isi reduced by graph
// locally (sorted graph_ids -> bucket spans few graphs), few global atomics.
__global__ void pool_kernel(const unsigned* __restrict__ dstP,
                            const unsigned* __restrict__ baseD, const unsigned* __restrict__ totD,
                            const float* __restrict__ sarr, const float* __restrict__ isiA,
                            const int* __restrict__ graph_ids,
                            float* __restrict__ Xsum, int N, int G) {
    __shared__ float t2h[BNODES];
    __shared__ float gXs[BNODES];
    for (int t = threadIdx.x; t < BNODES; t += TB) { t2h[t] = 0.0f; gXs[t] = 0.0f; }
    __syncthreads();
    int b = blockIdx.x;
    unsigned start = baseD[b], cnt = totD[b];
    for (unsigned i = threadIdx.x; i < cnt; i += TB) {
        unsigned e = dstP[start + i];
        atomicAdd(&t2h[e >> 19], sarr[e & 0x7FFFFu]);
    }
    __syncthreads();
    int nbase = b << BSH;
    int firstNode = nbase < N ? nbase : (N - 1);
    int g0 = graph_ids[firstNode];
    for (int t = threadIdx.x; t < BNODES; t += TB) {
        int node = nbase + t;
        if (node < N) {
            float x = t2h[t] * isiA[node];
            int gg = graph_ids[node] - g0;          // >= 0, < 1024 (G <= 1024)
            atomicAdd(&gXs[gg], x);
        }
    }
    __syncthreads();
    for (int t = threadIdx.x; t < BNODES; t += TB) {
        float v = gXs[t];
        if (v != 0.0f && g0 + t < G) atomicAdd(&Xsum[g0 + t], v);
    }
}

__global__ void final_kernel(const float* __restrict__ Xsum, const int* __restrict__ graph_ids,
                             const float* __restrict__ W1, const float* __restrict__ W2,
                             const float* __restrict__ Wlast,
                             float* __restrict__ out, int N, int GC) {
    int i = blockIdx.x * TB + threadIdx.x;
    if (i < GC) {
        int g = i >> 3, j = i & 7;
        int lo = 0, hi = N;
        while (lo < hi) { int m = (lo + hi) >> 1; if (graph_ids[m] < g) lo = m + 1; else hi = m; }
        int lo2 = lo, hi2 = N;
        while (lo2 < hi2) { int m = (lo2 + hi2) >> 1; if (graph_ids[m] < g + 1) lo2 = m + 1; else hi2 = m; }
        float c = (float)(lo2 - lo);
        float r = 0.0f;
#pragma unroll
        for (int cc = 0; cc < 8; ++cc) {
            float m = 0.0f;
#pragma unroll
            for (int k = 0; k < 8; ++k) m += fmaxf(W1[k], 0.0f) * W2[k * 8 + cc];
            r += fmaxf(m, 0.0f) * Wlast[cc * 8 + j];
        }
        out[i] = Xsum[g] / fmaxf(c, 1.0f) * r;
    }
}

// ======================= fallback (atomic) path =======================

__global__ void fb_deg_kernel(const int* __restrict__ src, const int* __restrict__ dst,
                              float* __restrict__ deg_out, float* __restrict__ deg_in, int E) {
    int i = blockIdx.x * TB + threadIdx.x;
    if (i < E) {
        atomicAdd(&deg_out[src[i]], 1.0f);
        atomicAdd(&deg_in[dst[i]], 1.0f);
    }
}

__global__ void fb_prep_kernel(const float* __restrict__ deg_in, const float* __restrict__ deg_out,
                               float* __restrict__ isi, float* __restrict__ iso,
                               float* __restrict__ h0s, int N) {
    int i = blockIdx.x * TB + threadIdx.x;
    if (i < N) {
        float di = deg_in[i], dn = deg_out[i];
        float a = 1.0f / sqrtf(fmaxf(di, 1.0f));
        float b = 1.0f / sqrtf(fmaxf(dn, 1.0f));
        isi[i] = a; iso[i] = b; h0s[i] = di * b;
    }
}

__global__ void fb_conv_kernel(const int* __restrict__ src, const int* __restrict__ dst,
                               const float* __restrict__ vals, float* __restrict__ t, int E) {
    int i = blockIdx.x * TB + threadIdx.x;
    if (i < E) atomicAdd(&t[dst[i]], vals[src[i]]);
}

__global__ void fb_mid_kernel(const float* __restrict__ agg1, const float* __restrict__ isi,
                              const float* __restrict__ iso, float* __restrict__ s, int N) {
    int i = blockIdx.x * TB + threadIdx.x;
    if (i < N) s[i] = agg1[i] * isi[i] * iso[i];
}

__global__ void fb_pool_kernel(const float* __restrict__ t2, const float* __restrict__ isi,
                               const int* __restrict__ graph_ids,
                               float* __restrict__ Xsum, float* __restrict__ counts, int N) {
    int i = blockIdx.x * TB + threadIdx.x;
    bool valid = i < N;
    int ii = valid ? i : (N - 1);
    float x = valid ? t2[ii] * isi[ii] : 0.0f;
    float cnt = valid ? 1.0f : 0.0f;
    int g = graph_ids[ii];
    int g0 = __shfl(g, 0, 64);
    bool uniform = __all((!valid) || (g == g0));
    if (uniform) {
#pragma unroll
        for (int off = 32; off >= 1; off >>= 1) {
            x += __shfl_down(x, off, 64);
            cnt += __shfl_down(cnt, off, 64);
        }
        if ((threadIdx.x & 63) == 0) { atomicAdd(&Xsum[g0], x); atomicAdd(&counts[g0], cnt); }
    } else if (valid) {
        atomicAdd(&Xsum[g], x); atomicAdd(&counts[g], 1.0f);
    }
}

__global__ void fb_final_kernel(const float* __restrict__ Xsum, const float* __restrict__ counts,
                                const float* __restrict__ W1, const float* __restrict__ W2,
                                const float* __restrict__ Wlast, float* __restrict__ out, int GC) {
    int i = blockIdx.x * TB + threadIdx.x;
    if (i < GC) {
        int g = i >> 3, j = i & 7;
        float r = 0.0f;
#pragma unroll
        for (int c = 0; c < 8; ++c) {
            float m = 0.0f;
#pragma unroll
            for (int k = 0; k < 8; ++k) m += fmaxf(W1[k], 0.0f) * W2[k * 8 + c];
            r += fmaxf(m, 0.0f) * Wlast[c * 8 + j];
        }
        out[i] = Xsum[g] / fmaxf(counts[g], 1.0f) * r;
    }
}

// ======================= launch =======================

extern "C" void kernel_launch(void* const* d_in, const int* in_sizes, int n_in,
                              void* d_out, int out_size, void* d_ws, size_t ws_size,
                              hipStream_t stream) {
    const float* W1        = (const float*)d_in[0];
    const float* W2        = (const float*)d_in[1];
    const float* Wlast     = (const float*)d_in[2];
    const int*   src       = (const int*)d_in[3];
    const int*   dst       = (const int*)d_in[4];
    const int*   graph_ids = (const int*)d_in[5];
    float* out = (float*)d_out;

    const int E = in_sizes[3];
    const int N = in_sizes[5];
    const int G = out_size / 8;

    int NB    = (N + BNODES - 1) >> BSH;
    int Npad  = NB << BSH;
    int NCH   = (E + CHUNK - 1) / CHUNK;
    int ITEMS = (NCH + TB - 1) / TB;

    char* basep = (char*)d_ws;
    size_t off = 0;
    auto A = [&](size_t bytes) { size_t o = off; off = (off + bytes + 63) & ~(size_t)63; return o; };

    size_t o_dstP  = A((size_t)E * 4);
    size_t o_srcP  = A((size_t)E * 2);
    size_t o_cntD  = A((size_t)NB * NCH * 4);
    size_t o_cntS  = A((size_t)NB * NCH * 4);
    size_t o_totD  = A((size_t)NB * 4);
    size_t o_totS  = A((size_t)NB * 4);
    size_t o_baseD = A((size_t)NB * 4);
    size_t o_baseS = A((size_t)NB * 4);
    size_t o_pio   = A((size_t)Npad * 4);
    size_t o_h0s   = A((size_t)Npad * 4);
    size_t o_isi   = A((size_t)Npad * 4);
    size_t o_s     = A((size_t)Npad * 4);
    size_t o_Xsum  = A((size_t)G * 4);
    size_t req = off;

    bool fast = (N <= (1 << 19)) && (G <= 1024) && (NB <= MAXNB) &&
                (ITEMS <= MAXITEMS) && (ws_size >= req) && (E >= 4);

    if (fast) {
        unsigned*       dstP  = (unsigned*)(basep + o_dstP);
        unsigned short* srcP  = (unsigned short*)(basep + o_srcP);
        unsigned* cntD  = (unsigned*)(basep + o_cntD);
        unsigned* cntS  = (unsigned*)(basep + o_cntS);
        unsigned* totD  = (unsigned*)(basep + o_totD);
        unsigned* totS  = (unsigned*)(basep + o_totS);
        unsigned* baseD = (unsigned*)(basep + o_baseD);
        unsigned* baseS = (unsigned*)(basep + o_baseS);
        float* pio  = (float*)(basep + o_pio);
        float* h0s  = (float*)(basep + o_h0s);
        float* isiA = (float*)(basep + o_isi);
        float* sarr = (float*)(basep + o_s);
        float* Xsum = (float*)(basep + o_Xsum);

        hipMemsetAsync(Xsum, 0, (size_t)G * 4, stream);
        count_kernel<<<NCH, TB, 0, stream>>>(src, dst, cntS, cntD, NB, NCH, E);
        scan_kernel<<<2 * NB, TB, 0, stream>>>(cntD, cntS, totD, totS, NB, NCH, ITEMS);
        base_kernel<<<1, 64, 0, stream>>>(totD, totS, baseD, baseS, NB);
        scatter_both_kernel<<<NCH, TB, 0, stream>>>(src, dst, cntS, cntD, baseS, baseD,
                                                    srcP, dstP, NB, NCH, E);
        degprep_kernel<<<NB, TB, 0, stream>>>(srcP, dstP, baseS, baseD, totS, totD,
                                              pio, h0s, isiA, N);
        conv1h_kernel<<<NB, TB, 0, stream>>>(dstP, baseD, totD, h0s, pio, sarr, NB);
        pool_kernel<<<NB, TB, 0, stream>>>(dstP, baseD, totD, sarr, isiA, graph_ids,
                                           Xsum, N, G);
        final_kernel<<<(out_size + TB - 1) / TB, TB, 0, stream>>>(Xsum, graph_ids,
                                                                  W1, W2, Wlast, out, N, out_size);
    } else {
        float* ws = (float*)d_ws;
        size_t f = 0;
        auto FA = [&](size_t n) { size_t o = f; f += (n + 3) & ~(size_t)3; return o; };
        size_t f_degin  = FA(N);
        size_t f_degout = FA(N);
        size_t f_agg1   = FA(N);
        size_t f_t2     = FA(N);
        size_t f_Xsum   = FA(G);
        size_t f_cnt    = FA(G);
        size_t zf = f;
        size_t f_isi = FA(N);
        size_t f_iso = FA(N);
        size_t f_h0s = FA(N);
        size_t f_s   = FA(N);
        hipMemsetAsync(ws, 0, zf * sizeof(float), stream);
        int gridE = (E + TB - 1) / TB;
        int gridN = (N + TB - 1) / TB;
        int gridO = (out_size + TB - 1) / TB;
        fb_deg_kernel<<<gridE, TB, 0, stream>>>(src, dst, ws + f_degout, ws + f_degin, E);
        fb_prep_kernel<<<gridN, TB, 0, stream>>>(ws + f_degin, ws + f_degout,
                                                 ws + f_isi, ws + f_iso, ws + f_h0s, N);
        fb_conv_kernel<<<gridE, TB, 0, stream>>>(src, dst, ws + f_h0s, ws + f_agg1, E);
        fb_mid_kernel<<<gridN, TB, 0, stream>>>(ws + f_agg1, ws + f_isi, ws + f_iso, ws + f_s, N);
        fb_conv_kernel<<<gridE, TB, 0, stream>>>(src, dst, ws + f_s, ws + f_t2, E);
        fb_pool_kernel<<<gridN, TB, 0, stream>>>(ws + f_t2, ws + f_isi, graph_ids,
                                                 ws + f_Xsum, ws + f_cnt, N);
        fb_final_kernel<<<gridO, TB, 0, stream>>>(ws + f_Xsum, ws + f_cnt, W1, W2, Wlast,
                                                  out, out_size);
    }
}

// Round 6
// 439.354 us; speedup vs baseline: 12.8548x; 1.2533x over previous
//
#include <hip/hip_runtime.h>

// GCN rank-1 collapse + bucket partition with LDS write-staging (R6).
// R5 evidence: scatter write-amp (6x) is L2 dirty-line eviction under the
// streaming read, not chunk-boundary sharing -> write-combine in LDS instead.
// 62 buckets of 8192 nodes; payload (dst_local:13<<19)|src:19 = u32 exactly.
// Scatter stages 64 entries/bucket in LDS, flushes 128 B runs; overflow path
// does direct stores. Downstream: packed deg hist, conv1 hist, pool hist as
// per-bucket LDS histograms with J sub-blocks + partial reduce.

#define TB 256
#define BSH 13
#define BNODES 8192
#define MAXNB 64
#define CHUNK 16384
#define QPB (CHUNK / 4 / TB)
#define KST 64
#define MAXITEMS 8

// ---------------- count / scan / base ----------------

__global__ void count_kernel(const int* __restrict__ src, const int* __restrict__ dst,
                             unsigned* __restrict__ cntS, unsigned* __restrict__ cntD,
                             int NB, int NCH, int E) {
    __shared__ unsigned cs[MAXNB], cd[MAXNB];
    for (int b = threadIdx.x; b < NB; b += TB) { cs[b] = 0u; cd[b] = 0u; }
    __syncthreads();
    int blk = blockIdx.x;
    int q0 = blk * (CHUNK / 4);
    int Eq = E >> 2;
#pragma unroll 4
    for (int it = 0; it < QPB; ++it) {
        int q = q0 + it * TB + threadIdx.x;
        if (q < Eq) {
            int4 s4 = ((const int4*)src)[q];
            int4 d4 = ((const int4*)dst)[q];
            atomicAdd(&cs[(unsigned)s4.x >> BSH], 1u);
            atomicAdd(&cs[(unsigned)s4.y >> BSH], 1u);
            atomicAdd(&cs[(unsigned)s4.z >> BSH], 1u);
            atomicAdd(&cs[(unsigned)s4.w >> BSH], 1u);
            atomicAdd(&cd[(unsigned)d4.x >> BSH], 1u);
            atomicAdd(&cd[(unsigned)d4.y >> BSH], 1u);
            atomicAdd(&cd[(unsigned)d4.z >> BSH], 1u);
            atomicAdd(&cd[(unsigned)d4.w >> BSH], 1u);
        }
    }
    if (blk == gridDim.x - 1) {
        for (int j = (Eq << 2) + threadIdx.x; j < E; j += TB) {
            atomicAdd(&cs[(unsigned)src[j] >> BSH], 1u);
            atomicAdd(&cd[(unsigned)dst[j] >> BSH], 1u);
        }
    }
    __syncthreads();
    for (int b = threadIdx.x; b < NB; b += TB) {
        cntS[(size_t)b * NCH + blk] = cs[b];
        cntD[(size_t)b * NCH + blk] = cd[b];
    }
}

__global__ void scan_kernel(unsigned* __restrict__ cntD, unsigned* __restrict__ cntS,
                            unsigned* __restrict__ totD, unsigned* __restrict__ totS,
                            int NB, int NCH, int ITEMS) {
    int bi = blockIdx.x;
    unsigned* row;
    unsigned* tot;
    int b;
    if (bi < NB) { b = bi; row = cntD + (size_t)b * NCH; tot = totD; }
    else         { b = bi - NB; row = cntS + (size_t)b * NCH; tot = totS; }
    unsigned v[MAXITEMS];
    unsigned sum = 0;
    int base = threadIdx.x * ITEMS;
    for (int k = 0; k < ITEMS; ++k) {
        int idx = base + k;
        unsigned x = (idx < NCH) ? row[idx] : 0u;
        v[k] = x;
        sum += x;
    }
    __shared__ unsigned wsum[TB];
    wsum[threadIdx.x] = sum;
    __syncthreads();
    if (threadIdx.x == 0) {
        unsigned carry = 0;
        for (int i = 0; i < TB; ++i) { unsigned t = wsum[i]; wsum[i] = carry; carry += t; }
        tot[b] = carry;
    }
    __syncthreads();
    unsigned run = wsum[threadIdx.x];
    for (int k = 0; k < ITEMS; ++k) {
        int idx = base + k;
        if (idx < NCH) { unsigned old = v[k]; row[idx] = run; run += old; }
    }
}

__global__ void base_kernel(const unsigned* __restrict__ totD, const unsigned* __restrict__ totS,
                            unsigned* __restrict__ baseD, unsigned* __restrict__ baseS, int NB) {
    if (threadIdx.x == 0 && blockIdx.x == 0) {
        unsigned c = 0;
        for (int b = 0; b < NB; ++b) { baseD[b] = c; c += totD[b]; }
        c = 0;
        for (int b = 0; b < NB; ++b) { baseS[b] = c; c += totS[b]; }
    }
}

// ---------------- scatter with LDS write-staging ----------------

__global__ void scatter_kernel(const int* __restrict__ src, const int* __restrict__ dst,
                               const unsigned* __restrict__ cntS, const unsigned* __restrict__ cntD,
                               const unsigned* __restrict__ baseS, const unsigned* __restrict__ baseD,
                               unsigned short* __restrict__ srcP, unsigned* __restrict__ dstP,
                               int NB, int NCH, int E) {
    __shared__ unsigned sdStage[MAXNB * KST];        // 16 KB
    __shared__ unsigned short ssStage[MAXNB * KST];  // 8 KB
    __shared__ unsigned dCnt[MAXNB], sCnt[MAXNB], dG[MAXNB], sG[MAXNB];
    int blk = blockIdx.x;
    for (int b = threadIdx.x; b < NB; b += TB) {
        dG[b] = baseD[b] + cntD[(size_t)b * NCH + blk];
        sG[b] = baseS[b] + cntS[(size_t)b * NCH + blk];
        dCnt[b] = 0u; sCnt[b] = 0u;
    }
    __syncthreads();
    int q0 = blk * (CHUNK / 4);
    int Eq = E >> 2;
    int bf = threadIdx.x >> 2;     // flush bucket (4 threads per bucket, same wave)
    int l4 = threadIdx.x & 3;
    for (int it = 0; it < QPB; ++it) {
        int q = q0 + it * TB + threadIdx.x;
        unsigned ovPayD[4], ovBD[4], ovBS[4];
        unsigned short ovValS[4];
        bool ovFD[4] = {false, false, false, false};
        bool ovFS[4] = {false, false, false, false};
        if (q < Eq) {
            int4 s4 = ((const int4*)src)[q];
            int4 d4 = ((const int4*)dst)[q];
            int ss[4] = {s4.x, s4.y, s4.z, s4.w};
            int dd[4] = {d4.x, d4.y, d4.z, d4.w};
#pragma unroll
            for (int k = 0; k < 4; ++k) {
                unsigned s = (unsigned)ss[k], d = (unsigned)dd[k];
                unsigned bd = d >> BSH;
                unsigned pay = ((d & (BNODES - 1)) << 19) | s;
                unsigned pos = atomicAdd(&dCnt[bd], 1u);
                if (pos < KST) sdStage[bd * KST + pos] = pay;
                else { ovFD[k] = true; ovPayD[k] = pay; ovBD[k] = bd; }
                unsigned bs = s >> BSH;
                unsigned short val = (unsigned short)(s & (BNODES - 1));
                unsigned pos2 = atomicAdd(&sCnt[bs], 1u);
                if (pos2 < KST) ssStage[bs * KST + pos2] = val;
                else { ovFS[k] = true; ovValS[k] = val; ovBS[k] = bs; }
            }
        }
        __syncthreads();
        if (bf < NB) {
            unsigned nD = min(dCnt[bf], (unsigned)KST);
            unsigned nfD = nD & ~31u;
            unsigned gD = dG[bf];
            for (unsigned i = l4; i < nfD; i += 4) dstP[gD + i] = sdStage[bf * KST + i];
            unsigned nS = min(sCnt[bf], (unsigned)KST);
            unsigned nfS = nS & ~31u;
            unsigned gS = sG[bf];
            for (unsigned i = l4; i < nfS; i += 4) srcP[gS + i] = ssStage[bf * KST + i];
            unsigned remD = nD - nfD, remS = nS - nfS;
            // slot->thread mapping identical to flush loop (slot%4): per-lane
            // program order + in-order DS pipe make this race-free.
            for (unsigned i = l4; i < remD; i += 4) sdStage[bf * KST + i] = sdStage[bf * KST + nfD + i];
            for (unsigned i = l4; i < remS; i += 4) ssStage[bf * KST + i] = ssStage[bf * KST + nfS + i];
            if (l4 == 0) {
                dG[bf] = gD + nfD; sG[bf] = gS + nfS;
                dCnt[bf] = remD;   sCnt[bf] = remS;
            }
        }
        __syncthreads();
#pragma unroll
        for (int k = 0; k < 4; ++k) {
            if (ovFD[k]) { unsigned p = atomicAdd(&dG[ovBD[k]], 1u); dstP[p] = ovPayD[k]; }
            if (ovFS[k]) { unsigned p = atomicAdd(&sG[ovBS[k]], 1u); srcP[p] = ovValS[k]; }
        }
        __syncthreads();
    }
    if (blk == NCH - 1) {   // E % 4 tail, direct stores
        for (int j2 = (Eq << 2) + threadIdx.x; j2 < E; j2 += TB) {
            unsigned s = (unsigned)src[j2], d = (unsigned)dst[j2];
            unsigned p = atomicAdd(&dG[d >> BSH], 1u);
            dstP[p] = ((d & (BNODES - 1)) << 19) | s;
            unsigned p2 = atomicAdd(&sG[s >> BSH], 1u);
            srcP[p2] = (unsigned short)(s & (BNODES - 1));
        }
    }
    __syncthreads();
    if (bf < NB) {   // final flush of remainders (<32 per bucket)
        unsigned n = dCnt[bf], g = dG[bf];
        for (unsigned i = l4; i < n; i += 4) dstP[g + i] = sdStage[bf * KST + i];
        unsigned n2 = sCnt[bf], g2 = sG[bf];
        for (unsigned i = l4; i < n2; i += 4) srcP[g2 + i] = ssStage[bf * KST + i];
    }
}

// ---------------- per-bucket histograms ----------------

// Packed degrees: high16 = deg_in (from dstP), low16 = deg_out (from srcP).
__global__ void deghist_kernel(const unsigned short* __restrict__ srcP, const unsigned* __restrict__ dstP,
                               const unsigned* __restrict__ baseS, const unsigned* __restrict__ baseD,
                               const unsigned* __restrict__ totS, const unsigned* __restrict__ totD,
                               unsigned* __restrict__ pDeg, int Jlg) {
    __shared__ unsigned h[BNODES];
    for (int t = threadIdx.x; t < BNODES; t += TB) h[t] = 0u;
    __syncthreads();
    int J = 1 << Jlg;
    int b = blockIdx.x >> Jlg;
    int j = blockIdx.x & (J - 1);
    unsigned cD = totD[b], sD = baseD[b];
    unsigned lo = (unsigned)(((unsigned long long)cD * (unsigned)j) >> Jlg);
    unsigned hi = (unsigned)(((unsigned long long)cD * (unsigned)(j + 1)) >> Jlg);
    for (unsigned i = lo + threadIdx.x; i < hi; i += TB)
        atomicAdd(&h[dstP[sD + i] >> 19], 0x10000u);
    unsigned cS = totS[b], sS = baseS[b];
    unsigned lo2 = (unsigned)(((unsigned long long)cS * (unsigned)j) >> Jlg);
    unsigned hi2 = (unsigned)(((unsigned long long)cS * (unsigned)(j + 1)) >> Jlg);
    for (unsigned i = lo2 + threadIdx.x; i < hi2; i += TB)
        atomicAdd(&h[srcP[sS + i]], 1u);
    __syncthreads();
    unsigned* row = pDeg + (size_t)blockIdx.x * BNODES;
    for (int t = threadIdx.x; t < BNODES; t += TB) row[t] = h[t];
}

__global__ void prep_kernel(const unsigned* __restrict__ pDeg,
                            float* __restrict__ pio, float* __restrict__ h0s,
                            float* __restrict__ isiA, int Jlg, int Npad) {
    int i = blockIdx.x * TB + threadIdx.x;
    if (i >= Npad) return;
    int b = i >> BSH, l = i & (BNODES - 1);
    int J = 1 << Jlg;
    unsigned sum = 0;
    for (int j = 0; j < J; ++j)
        sum += pDeg[(size_t)((b << Jlg) + j) * BNODES + l];
    float din = (float)(sum >> 16), dout = (float)(sum & 0xFFFFu);
    float a  = 1.0f / sqrtf(fmaxf(din, 1.0f));    // inv_sqrt_in
    float bo = 1.0f / sqrtf(fmaxf(dout, 1.0f));   // inv_sqrt_out
    pio[i]  = a * bo;
    h0s[i]  = din * bo;
    isiA[i] = a;
}

// Weighted histogram over dstP: hist[dst_local] += table[src]. Used for conv1
// (table = h0s) and conv2/pool (table = sarr).
__global__ void wh_kernel(const unsigned* __restrict__ dstP,
                          const unsigned* __restrict__ baseD, const unsigned* __restrict__ totD,
                          const float* __restrict__ table, float* __restrict__ pOut, int Jlg) {
    __shared__ float h[BNODES];
    for (int t = threadIdx.x; t < BNODES; t += TB) h[t] = 0.0f;
    __syncthreads();
    int J = 1 << Jlg;
    int b = blockIdx.x >> Jlg;
    int j = blockIdx.x & (J - 1);
    unsigned cD = totD[b], sD = baseD[b];
    unsigned lo = (unsigned)(((unsigned long long)cD * (unsigned)j) >> Jlg);
    unsigned hi = (unsigned)(((unsigned long long)cD * (unsigned)(j + 1)) >> Jlg);
    for (unsigned i = lo + threadIdx.x; i < hi; i += TB) {
        unsigned e = dstP[sD + i];
        atomicAdd(&h[e >> 19], table[e & 0x7FFFFu]);
    }
    __syncthreads();
    float* row = pOut + (size_t)blockIdx.x * BNODES;
    for (int t = threadIdx.x; t < BNODES; t += TB) row[t] = h[t];
}

__global__ void mid_kernel(const float* __restrict__ pC, const float* __restrict__ pio,
                           float* __restrict__ sarr, int Jlg, int Npad) {
    int i = blockIdx.x * TB + threadIdx.x;
    if (i >= Npad) return;
    int b = i >> BSH, l = i & (BNODES - 1);
    int J = 1 << Jlg;
    float t1 = 0.0f;
    for (int j = 0; j < J; ++j)
        t1 += pC[(size_t)((b << Jlg) + j) * BNODES + l];
    sarr[i] = t1 * pio[i];
}

__global__ void poolfinal_kernel(const float* __restrict__ pT, const float* __restrict__ isiA,
                                 const int* __restrict__ graph_ids,
                                 float* __restrict__ Xsum, int Jlg, int N) {
    int i = blockIdx.x * TB + threadIdx.x;
    bool valid = i < N;
    int ii = valid ? i : (N - 1);
    int b = ii >> BSH, l = ii & (BNODES - 1);
    int J = 1 << Jlg;
    float t2 = 0.0f;
    for (int j = 0; j < J; ++j)
        t2 += pT[(size_t)((b << Jlg) + j) * BNODES + l];
    float x = valid ? t2 * isiA[ii] : 0.0f;
    int g = graph_ids[ii];
    int g0 = __shfl(g, 0, 64);
    bool uniform = __all((!valid) || (g == g0));
    if (uniform) {
#pragma unroll
        for (int off = 32; off >= 1; off >>= 1) x += __shfl_down(x, off, 64);
        if ((threadIdx.x & 63) == 0) atomicAdd(&Xsum[g0], x);
    } else if (valid) {
        atomicAdd(&Xsum[g], x);
    }
}

__global__ void final_kernel(const float* __restrict__ Xsum, const int* __restrict__ graph_ids,
                             const float* __restrict__ W1, const float* __restrict__ W2,
                             const float* __restrict__ Wlast,
                             float* __restrict__ out, int N, int GC) {
    int i = blockIdx.x * TB + threadIdx.x;
    if (i < GC) {
        int g = i >> 3, j = i & 7;
        int lo = 0, hi = N;
        while (lo < hi) { int m = (lo + hi) >> 1; if (graph_ids[m] < g) lo = m + 1; else hi = m; }
        int lo2 = lo, hi2 = N;
        while (lo2 < hi2) { int m = (lo2 + hi2) >> 1; if (graph_ids[m] < g + 1) lo2 = m + 1; else hi2 = m; }
        float c = (float)(lo2 - lo);
        float r = 0.0f;
#pragma unroll
        for (int cc = 0; cc < 8; ++cc) {
            float m = 0.0f;
#pragma unroll
            for (int k = 0; k < 8; ++k) m += fmaxf(W1[k], 0.0f) * W2[k * 8 + cc];
            r += fmaxf(m, 0.0f) * Wlast[cc * 8 + j];
        }
        out[i] = Xsum[g] / fmaxf(c, 1.0f) * r;
    }
}

// ---------------- fallback (atomic) path ----------------

__global__ void fb_deg_kernel(const int* __restrict__ src, const int* __restrict__ dst,
                              float* __restrict__ deg_out, float* __restrict__ deg_in, int E) {
    int i = blockIdx.x * TB + threadIdx.x;
    if (i < E) {
        atomicAdd(&deg_out[src[i]], 1.0f);
        atomicAdd(&deg_in[dst[i]], 1.0f);
    }
}

__global__ void fb_prep_kernel(const float* __restrict__ deg_in, const float* __restrict__ deg_out,
                               float* __restrict__ isi, float* __restrict__ iso,
                               float* __restrict__ h0s, int N) {
    int i = blockIdx.x * TB + threadIdx.x;
    if (i < N) {
        float di = deg_in[i], dn = deg_out[i];
        float a = 1.0f / sqrtf(fmaxf(di, 1.0f));
        float b = 1.0f / sqrtf(fmaxf(dn, 1.0f));
        isi[i] = a; iso[i] = b; h0s[i] = di * b;
    }
}

__global__ void fb_conv_kernel(const int* __restrict__ src, const int* __restrict__ dst,
                               const float* __restrict__ vals, float* __restrict__ t, int E) {
    int i = blockIdx.x * TB + threadIdx.x;
    if (i < E) atomicAdd(&t[dst[i]], vals[src[i]]);
}

__global__ void fb_mid_kernel(const float* __restrict__ agg1, const float* __restrict__ isi,
                              const float* __restrict__ iso, float* __restrict__ s, int N) {
    int i = blockIdx.x * TB + threadIdx.x;
    if (i < N) s[i] = agg1[i] * isi[i] * iso[i];
}

__global__ void fb_pool_kernel(const float* __restrict__ t2, const float* __restrict__ isi,
                               const int* __restrict__ graph_ids,
                               float* __restrict__ Xsum, float* __restrict__ counts, int N) {
    int i = blockIdx.x * TB + threadIdx.x;
    bool valid = i < N;
    int ii = valid ? i : (N - 1);
    float x = valid ? t2[ii] * isi[ii] : 0.0f;
    float cnt = valid ? 1.0f : 0.0f;
    int g = graph_ids[ii];
    int g0 = __shfl(g, 0, 64);
    bool uniform = __all((!valid) || (g == g0));
    if (uniform) {
#pragma unroll
        for (int off = 32; off >= 1; off >>= 1) {
            x += __shfl_down(x, off, 64);
            cnt += __shfl_down(cnt, off, 64);
        }
        if ((threadIdx.x & 63) == 0) { atomicAdd(&Xsum[g0], x); atomicAdd(&counts[g0], cnt); }
    } else if (valid) {
        atomicAdd(&Xsum[g], x); atomicAdd(&counts[g], 1.0f);
    }
}

__global__ void fb_final_kernel(const float* __restrict__ Xsum, const float* __restrict__ counts,
                                const float* __restrict__ W1, const float* __restrict__ W2,
                                const float* __restrict__ Wlast, float* __restrict__ out, int GC) {
    int i = blockIdx.x * TB + threadIdx.x;
    if (i < GC) {
        int g = i >> 3, j = i & 7;
        float r = 0.0f;
#pragma unroll
        for (int c = 0; c < 8; ++c) {
            float m = 0.0f;
#pragma unroll
            for (int k = 0; k < 8; ++k) m += fmaxf(W1[k], 0.0f) * W2[k * 8 + c];
            r += fmaxf(m, 0.0f) * Wlast[c * 8 + j];
        }
        out[i] = Xsum[g] / fmaxf(counts[g], 1.0f) * r;
    }
}

// ---------------- launch ----------------

extern "C" void kernel_launch(void* const* d_in, const int* in_sizes, int n_in,
                              void* d_out, int out_size, void* d_ws, size_t ws_size,
                              hipStream_t stream) {
    const float* W1        = (const float*)d_in[0];
    const float* W2        = (const float*)d_in[1];
    const float* Wlast     = (const float*)d_in[2];
    const int*   src       = (const int*)d_in[3];
    const int*   dst       = (const int*)d_in[4];
    const int*   graph_ids = (const int*)d_in[5];
    float* out = (float*)d_out;

    const int E = in_sizes[3];
    const int N = in_sizes[5];
    const int G = out_size / 8;

    int NB    = (N + BNODES - 1) >> BSH;
    int Npad  = NB << BSH;
    int NCH   = (E + CHUNK - 1) / CHUNK;
    int ITEMS = (NCH + TB - 1) / TB;

    // Pick largest J in {8,4,2,1} whose layout fits ws.
    int Jlg = 3;
    size_t req = 0;
    size_t o_dstP, o_srcP, o_cntD, o_cntS, o_totD, o_totS, o_baseD, o_baseS,
           o_part, o_pio, o_h0sar, o_isi, o_Xsum;
    for (;; --Jlg) {
        int J = 1 << Jlg;
        size_t off = 0;
        auto A = [&](size_t bytes) { size_t o = off; off = (off + bytes + 127) & ~(size_t)127; return o; };
        o_dstP  = A((size_t)E * 4);
        o_srcP  = A((size_t)E * 2);
        o_cntD  = A((size_t)NB * NCH * 4);
        o_cntS  = A((size_t)NB * NCH * 4);
        o_totD  = A((size_t)NB * 4);
        o_totS  = A((size_t)NB * 4);
        o_baseD = A((size_t)NB * 4);
        o_baseS = A((size_t)NB * 4);
        o_part  = A((size_t)NB * J * BNODES * 4);  // pDeg, then pC, then pT
        o_pio   = A((size_t)Npad * 4);
        o_h0sar = A((size_t)Npad * 4);             // h0s, then sarr
        o_isi   = A((size_t)Npad * 4);
        o_Xsum  = A((size_t)G * 4);
        req = off;
        if (req <= ws_size || Jlg == 0) break;
    }

    bool fast = (N <= (1 << 19)) && (NB <= MAXNB) && (ITEMS <= MAXITEMS) &&
                (ws_size >= req) && (E >= 4);

    char* bp = (char*)d_ws;

    if (fast) {
        unsigned*       dstP  = (unsigned*)(bp + o_dstP);
        unsigned short* srcP  = (unsigned short*)(bp + o_srcP);
        unsigned* cntD  = (unsigned*)(bp + o_cntD);
        unsigned* cntS  = (unsigned*)(bp + o_cntS);
        unsigned* totD  = (unsigned*)(bp + o_totD);
        unsigned* totS  = (unsigned*)(bp + o_totS);
        unsigned* baseD = (unsigned*)(bp + o_baseD);
        unsigned* baseS = (unsigned*)(bp + o_baseS);
        unsigned* pDeg  = (unsigned*)(bp + o_part);
        float*    pC    = (float*)(bp + o_part);    // alias: pDeg dead after prep
        float*    pT    = (float*)(bp + o_part);    // alias: pC dead after mid
        float* pio  = (float*)(bp + o_pio);
        float* h0s  = (float*)(bp + o_h0sar);
        float* sarr = (float*)(bp + o_h0sar);       // alias: h0s dead after conv1
        float* isiA = (float*)(bp + o_isi);
        float* Xsum = (float*)(bp + o_Xsum);

        int gridNp = (Npad + TB - 1) / TB;
        int gridN  = (N + TB - 1) / TB;
        int J = 1 << Jlg;

        hipMemsetAsync(Xsum, 0, (size_t)G * 4, stream);
        count_kernel<<<NCH, TB, 0, stream>>>(src, dst, cntS, cntD, NB, NCH, E);
        scan_kernel<<<2 * NB, TB, 0, stream>>>(cntD, cntS, totD, totS, NB, NCH, ITEMS);
        base_kernel<<<1, 64, 0, stream>>>(totD, totS, baseD, baseS, NB);
        scatter_kernel<<<NCH, TB, 0, stream>>>(src, dst, cntS, cntD, baseS, baseD,
                                               srcP, dstP, NB, NCH, E);
        deghist_kernel<<<NB * J, TB, 0, stream>>>(srcP, dstP, baseS, baseD, totS, totD,
                                                  pDeg, Jlg);
        prep_kernel<<<gridNp, TB, 0, stream>>>(pDeg, pio, h0s, isiA, Jlg, Npad);
        wh_kernel<<<NB * J, TB, 0, stream>>>(dstP, baseD, totD, h0s, pC, Jlg);
        mid_kernel<<<gridNp, TB, 0, stream>>>(pC, pio, sarr, Jlg, Npad);
        wh_kernel<<<NB * J, TB, 0, stream>>>(dstP, baseD, totD, sarr, pT, Jlg);
        poolfinal_kernel<<<gridN, TB, 0, stream>>>(pT, isiA, graph_ids, Xsum, Jlg, N);
        final_kernel<<<(out_size + TB - 1) / TB, TB, 0, stream>>>(Xsum, graph_ids,
                                                                  W1, W2, Wlast, out, N, out_size);
    } else {
        float* ws = (float*)d_ws;
        size_t f = 0;
        auto FA = [&](size_t n) { size_t o = f; f += (n + 3) & ~(size_t)3; return o; };
        size_t f_degin  = FA(N);
        size_t f_degout = FA(N);
        size_t f_agg1   = FA(N);
        size_t f_t2     = FA(N);
        size_t f_Xsum   = FA(G);
        size_t f_cnt    = FA(G);
        size_t zf = f;
        size_t f_isi = FA(N);
        size_t f_iso = FA(N);
        size_t f_h0s = FA(N);
        size_t f_s   = FA(N);
        hipMemsetAsync(ws, 0, zf * sizeof(float), stream);
        int gridE = (E + TB - 1) / TB;
        int gridN = (N + TB - 1) / TB;
        int gridO = (out_size + TB - 1) / TB;
        fb_deg_kernel<<<gridE, TB, 0, stream>>>(src, dst, ws + f_degout, ws + f_degin, E);
        fb_prep_kernel<<<gridN, TB, 0, stream>>>(ws + f_degin, ws + f_degout,
                                                 ws + f_isi, ws + f_iso, ws + f_h0s, N);
        fb_conv_kernel<<<gridE, TB, 0, stream>>>(src, dst, ws + f_h0s, ws + f_agg1, E);
        fb_mid_kernel<<<gridN, TB, 0, stream>>>(ws + f_agg1, ws + f_isi, ws + f_iso, ws + f_s, N);
        fb_conv_kernel<<<gridE, TB, 0, stream>>>(src, dst, ws + f_s, ws + f_t2, E);
        fb_pool_kernel<<<gridN, TB, 0, stream>>>(ws + f_t2, ws + f_isi, graph_ids,
                                                 ws + f_Xsum, ws + f_cnt, N);
        fb_final_kernel<<<gridO, TB, 0, stream>>>(ws + f_Xsum, ws + f_cnt, W1, W2, Wlast,
                                                  out, out_size);
    }
}

// Round 7
// 431.078 us; speedup vs baseline: 13.1017x; 1.0192x over previous
//
#include <hip/hip_runtime.h>

// GCN rank-1 collapse + one-pass counting-sort bucket partition (R7).
// R6 evidence: LDS write-staging fixed scatter write-amp (88 MB for 60 MB
// payload). R7 removes the separate count/scan/base passes: each block sorts
// its 2048 edges by bucket in LDS (exact local counts -> wave scan -> global
// cursor reservation -> ordered staging -> contiguous flush). Bucket regions
// are fixed-capacity (E/NB + 20-sigma margin); totals come from the cursors.
// 62 buckets x 8192 nodes; dst payload (dst_local:13<<19)|src:19 = u32.

#define TB 256
#define BSH 13
#define BNODES 8192
#define MAXNB 64
#define SCH 2048
#define SCH4 (SCH / 4)
#define EPT 8
#define INVB 0xFFFFFFFFu

__global__ void init_kernel(unsigned* __restrict__ curD, unsigned* __restrict__ curS,
                            float* __restrict__ Xsum, int NB, unsigned CAP, int G) {
    int i = blockIdx.x * TB + threadIdx.x;
    if (i < NB) { curD[i] = (unsigned)i * CAP; curS[i] = (unsigned)i * CAP; }
    if (i < G) Xsum[i] = 0.0f;
}

__global__ void scatter_sort_kernel(const int* __restrict__ src, const int* __restrict__ dst,
                                    unsigned* __restrict__ curD, unsigned* __restrict__ curS,
                                    unsigned* __restrict__ dstP, unsigned short* __restrict__ srcP,
                                    int NB, int E) {
    __shared__ unsigned cntD[MAXNB], cntS[MAXNB];     // counts -> insert cursors
    __shared__ unsigned deltaD[MAXNB], deltaS[MAXNB]; // globalBase - localExclusive
    __shared__ unsigned totD_s, totS_s;
    __shared__ unsigned payD[SCH];
    __shared__ unsigned short valS[SCH];
    __shared__ unsigned char mapD[SCH], mapS[SCH];

    int tid = threadIdx.x;
    if (tid < MAXNB) { cntD[tid] = 0u; cntS[tid] = 0u; }
    __syncthreads();

    unsigned sA[EPT], dA[EPT], bD[EPT], bS[EPT];
    int blk = blockIdx.x;
#pragma unroll
    for (int v = 0; v < 2; ++v) {
        int q = blk * SCH4 + v * TB + tid;
        int be = q * 4;
        if (be + 3 < E) {
            int4 s4 = ((const int4*)src)[q];
            int4 d4 = ((const int4*)dst)[q];
            sA[v*4+0] = (unsigned)s4.x; sA[v*4+1] = (unsigned)s4.y;
            sA[v*4+2] = (unsigned)s4.z; sA[v*4+3] = (unsigned)s4.w;
            dA[v*4+0] = (unsigned)d4.x; dA[v*4+1] = (unsigned)d4.y;
            dA[v*4+2] = (unsigned)d4.z; dA[v*4+3] = (unsigned)d4.w;
#pragma unroll
            for (int k = 0; k < 4; ++k) {
                bD[v*4+k] = dA[v*4+k] >> BSH;
                bS[v*4+k] = sA[v*4+k] >> BSH;
            }
        } else {
#pragma unroll
            for (int k = 0; k < 4; ++k) {
                int j = be + k;
                if (j < E) {
                    sA[v*4+k] = (unsigned)src[j];
                    dA[v*4+k] = (unsigned)dst[j];
                    bD[v*4+k] = dA[v*4+k] >> BSH;
                    bS[v*4+k] = sA[v*4+k] >> BSH;
                } else {
                    bD[v*4+k] = INVB; bS[v*4+k] = INVB;
                    sA[v*4+k] = 0u; dA[v*4+k] = 0u;
                }
            }
        }
    }

#pragma unroll
    for (int k = 0; k < EPT; ++k) {
        if (bD[k] != INVB) {
            atomicAdd(&cntD[bD[k]], 1u);
            atomicAdd(&cntS[bS[k]], 1u);
        }
    }
    __syncthreads();

    int wv = tid >> 6, ln = tid & 63;
    if (wv == 0) {
        unsigned x = (ln < NB) ? cntD[ln] : 0u;
        unsigned inc = x;
#pragma unroll
        for (int o = 1; o < 64; o <<= 1) {
            unsigned y = __shfl_up(inc, o, 64);
            if (ln >= o) inc += y;
        }
        unsigned exc = inc - x;
        if (ln < NB) {
            unsigned gb = atomicAdd(&curD[ln], x);   // exact reservation
            deltaD[ln] = gb - exc;
            cntD[ln] = exc;                          // insert cursor
        }
        if (ln == 63) totD_s = inc;
    } else if (wv == 1) {
        unsigned x = (ln < NB) ? cntS[ln] : 0u;
        unsigned inc = x;
#pragma unroll
        for (int o = 1; o < 64; o <<= 1) {
            unsigned y = __shfl_up(inc, o, 64);
            if (ln >= o) inc += y;
        }
        unsigned exc = inc - x;
        if (ln < NB) {
            unsigned gb = atomicAdd(&curS[ln], x);
            deltaS[ln] = gb - exc;
            cntS[ln] = exc;
        }
        if (ln == 63) totS_s = inc;
    }
    __syncthreads();

#pragma unroll
    for (int k = 0; k < EPT; ++k) {
        if (bD[k] != INVB) {
            unsigned p = atomicAdd(&cntD[bD[k]], 1u);
            payD[p] = ((dA[k] & (BNODES - 1)) << 19) | sA[k];
            mapD[p] = (unsigned char)bD[k];
            unsigned p2 = atomicAdd(&cntS[bS[k]], 1u);
            valS[p2] = (unsigned short)(sA[k] & (BNODES - 1));
            mapS[p2] = (unsigned char)bS[k];
        }
    }
    __syncthreads();

    unsigned tD = totD_s, tS = totS_s;
    for (unsigned i = tid; i < tD; i += TB) {
        unsigned b = mapD[i];
        dstP[deltaD[b] + i] = payD[i];   // delta[b]+i = gBase + (i - exc[b])
    }
    for (unsigned i = tid; i < tS; i += TB) {
        unsigned b = mapS[i];
        srcP[deltaS[b] + i] = valS[i];
    }
}

// Packed degrees per sub-block: high16 = deg_in (dstP), low16 = deg_out (srcP).
__global__ void deghist_kernel(const unsigned short* __restrict__ srcP, const unsigned* __restrict__ dstP,
                               const unsigned* __restrict__ curS, const unsigned* __restrict__ curD,
                               unsigned CAP, unsigned* __restrict__ pDeg, int Jlg) {
    __shared__ unsigned h[BNODES];
    for (int t = threadIdx.x; t < BNODES; t += TB) h[t] = 0u;
    __syncthreads();
    int b = blockIdx.x >> Jlg;
    int j = blockIdx.x & ((1 << Jlg) - 1);
    unsigned s0 = (unsigned)b * CAP;
    unsigned cD = curD[b] - s0;
    unsigned lo = (unsigned)(((unsigned long long)cD * (unsigned)j) >> Jlg);
    unsigned hi = (unsigned)(((unsigned long long)cD * (unsigned)(j + 1)) >> Jlg);
    for (unsigned i = lo + threadIdx.x; i < hi; i += TB)
        atomicAdd(&h[dstP[s0 + i] >> 19], 0x10000u);
    unsigned cS = curS[b] - s0;
    lo = (unsigned)(((unsigned long long)cS * (unsigned)j) >> Jlg);
    hi = (unsigned)(((unsigned long long)cS * (unsigned)(j + 1)) >> Jlg);
    for (unsigned i = lo + threadIdx.x; i < hi; i += TB)
        atomicAdd(&h[srcP[s0 + i]], 1u);
    __syncthreads();
    unsigned* row = pDeg + (size_t)blockIdx.x * BNODES;
    for (int t = threadIdx.x; t < BNODES; t += TB) row[t] = h[t];
}

__global__ void prep_kernel(const unsigned* __restrict__ pDeg,
                            float* __restrict__ pio, float* __restrict__ h0s,
                            float* __restrict__ isiA, int Jlg, int Npad) {
    int i = blockIdx.x * TB + threadIdx.x;
    if (i >= Npad) return;
    int b = i >> BSH, l = i & (BNODES - 1);
    int J = 1 << Jlg;
    unsigned sum = 0;
    for (int j = 0; j < J; ++j)
        sum += pDeg[(size_t)((b << Jlg) + j) * BNODES + l];
    float din = (float)(sum >> 16), dout = (float)(sum & 0xFFFFu);
    float a  = 1.0f / sqrtf(fmaxf(din, 1.0f));    // inv_sqrt_in
    float bo = 1.0f / sqrtf(fmaxf(dout, 1.0f));   // inv_sqrt_out
    pio[i]  = a * bo;
    h0s[i]  = din * bo;   // invalid pad nodes: din=0 -> 0, contribute nothing
    isiA[i] = a;
}

// Weighted histogram over dstP: h[dst_local] += table[src].
__global__ void wh_kernel(const unsigned* __restrict__ dstP, const unsigned* __restrict__ curD,
                          unsigned CAP, const float* __restrict__ table,
                          float* __restrict__ pOut, int Jlg) {
    __shared__ float h[BNODES];
    for (int t = threadIdx.x; t < BNODES; t += TB) h[t] = 0.0f;
    __syncthreads();
    int b = blockIdx.x >> Jlg;
    int j = blockIdx.x & ((1 << Jlg) - 1);
    unsigned s0 = (unsigned)b * CAP;
    unsigned cD = curD[b] - s0;
    unsigned lo = (unsigned)(((unsigned long long)cD * (unsigned)j) >> Jlg);
    unsigned hi = (unsigned)(((unsigned long long)cD * (unsigned)(j + 1)) >> Jlg);
    for (unsigned i = lo + threadIdx.x; i < hi; i += TB) {
        unsigned e = dstP[s0 + i];
        atomicAdd(&h[e >> 19], table[e & 0x7FFFFu]);
    }
    __syncthreads();
    float* row = pOut + (size_t)blockIdx.x * BNODES;
    for (int t = threadIdx.x; t < BNODES; t += TB) row[t] = h[t];
}

__global__ void mid_kernel(const float* __restrict__ pC, const float* __restrict__ pio,
                           float* __restrict__ sarr, int Jlg, int Npad) {
    int i = blockIdx.x * TB + threadIdx.x;
    if (i >= Npad) return;
    int b = i >> BSH, l = i & (BNODES - 1);
    int J = 1 << Jlg;
    float t1 = 0.0f;
    for (int j = 0; j < J; ++j)
        t1 += pC[(size_t)((b << Jlg) + j) * BNODES + l];
    sarr[i] = t1 * pio[i];
}

__global__ void poolfinal_kernel(const float* __restrict__ pT, const float* __restrict__ isiA,
                                 const int* __restrict__ graph_ids,
                                 float* __restrict__ Xsum, int Jlg, int N) {
    int i = blockIdx.x * TB + threadIdx.x;
    bool valid = i < N;
    int ii = valid ? i : (N - 1);
    int b = ii >> BSH, l = ii & (BNODES - 1);
    int J = 1 << Jlg;
    float t2 = 0.0f;
    for (int j = 0; j < J; ++j)
        t2 += pT[(size_t)((b << Jlg) + j) * BNODES + l];
    float x = valid ? t2 * isiA[ii] : 0.0f;
    int g = graph_ids[ii];
    int g0 = __shfl(g, 0, 64);
    bool uniform = __all((!valid) || (g == g0));
    if (uniform) {
#pragma unroll
        for (int off = 32; off >= 1; off >>= 1) x += __shfl_down(x, off, 64);
        if ((threadIdx.x & 63) == 0) atomicAdd(&Xsum[g0], x);
    } else if (valid) {
        atomicAdd(&Xsum[g], x);
    }
}

__global__ void final_kernel(const float* __restrict__ Xsum, const int* __restrict__ graph_ids,
                             const float* __restrict__ W1, const float* __restrict__ W2,
                             const float* __restrict__ Wlast,
                             float* __restrict__ out, int N, int GC) {
    int i = blockIdx.x * TB + threadIdx.x;
    if (i < GC) {
        int g = i >> 3, j = i & 7;
        int lo = 0, hi = N;
        while (lo < hi) { int m = (lo + hi) >> 1; if (graph_ids[m] < g) lo = m + 1; else hi = m; }
        int lo2 = lo, hi2 = N;
        while (lo2 < hi2) { int m = (lo2 + hi2) >> 1; if (graph_ids[m] < g + 1) lo2 = m + 1; else hi2 = m; }
        float c = (float)(lo2 - lo);
        float r = 0.0f;
#pragma unroll
        for (int cc = 0; cc < 8; ++cc) {
            float m = 0.0f;
#pragma unroll
            for (int k = 0; k < 8; ++k) m += fmaxf(W1[k], 0.0f) * W2[k * 8 + cc];
            r += fmaxf(m, 0.0f) * Wlast[cc * 8 + j];
        }
        out[i] = Xsum[g] / fmaxf(c, 1.0f) * r;
    }
}

// ---------------- fallback (atomic) path ----------------

__global__ void fb_deg_kernel(const int* __restrict__ src, const int* __restrict__ dst,
                              float* __restrict__ deg_out, float* __restrict__ deg_in, int E) {
    int i = blockIdx.x * TB + threadIdx.x;
    if (i < E) {
        atomicAdd(&deg_out[src[i]], 1.0f);
        atomicAdd(&deg_in[dst[i]], 1.0f);
    }
}

__global__ void fb_prep_kernel(const float* __restrict__ deg_in, const float* __restrict__ deg_out,
                               float* __restrict__ isi, float* __restrict__ iso,
                               float* __restrict__ h0s, int N) {
    int i = blockIdx.x * TB + threadIdx.x;
    if (i < N) {
        float di = deg_in[i], dn = deg_out[i];
        float a = 1.0f / sqrtf(fmaxf(di, 1.0f));
        float b = 1.0f / sqrtf(fmaxf(dn, 1.0f));
        isi[i] = a; iso[i] = b; h0s[i] = di * b;
    }
}

__global__ void fb_conv_kernel(const int* __restrict__ src, const int* __restrict__ dst,
                               const float* __restrict__ vals, float* __restrict__ t, int E) {
    int i = blockIdx.x * TB + threadIdx.x;
    if (i < E) atomicAdd(&t[dst[i]], vals[src[i]]);
}

__global__ void fb_mid_kernel(const float* __restrict__ agg1, const float* __restrict__ isi,
                              const float* __restrict__ iso, float* __restrict__ s, int N) {
    int i = blockIdx.x * TB + threadIdx.x;
    if (i < N) s[i] = agg1[i] * isi[i] * iso[i];
}

__global__ void fb_pool_kernel(const float* __restrict__ t2, const float* __restrict__ isi,
                               const int* __restrict__ graph_ids,
                               float* __restrict__ Xsum, float* __restrict__ counts, int N) {
    int i = blockIdx.x * TB + threadIdx.x;
    bool valid = i < N;
    int ii = valid ? i : (N - 1);
    float x = valid ? t2[ii] * isi[ii] : 0.0f;
    float cnt = valid ? 1.0f : 0.0f;
    int g = graph_ids[ii];
    int g0 = __shfl(g, 0, 64);
    bool uniform = __all((!valid) || (g == g0));
    if (uniform) {
#pragma unroll
        for (int off = 32; off >= 1; off >>= 1) {
            x += __shfl_down(x, off, 64);
            cnt += __shfl_down(cnt, off, 64);
        }
        if ((threadIdx.x & 63) == 0) { atomicAdd(&Xsum[g0], x); atomicAdd(&counts[g0], cnt); }
    } else if (valid) {
        atomicAdd(&Xsum[g], x); atomicAdd(&counts[g], 1.0f);
    }
}

__global__ void fb_final_kernel(const float* __restrict__ Xsum, const float* __restrict__ counts,
                                const float* __restrict__ W1, const float* __restrict__ W2,
                                const float* __restrict__ Wlast, float* __restrict__ out, int GC) {
    int i = blockIdx.x * TB + threadIdx.x;
    if (i < GC) {
        int g = i >> 3, j = i & 7;
        float r = 0.0f;
#pragma unroll
        for (int c = 0; c < 8; ++c) {
            float m = 0.0f;
#pragma unroll
            for (int k = 0; k < 8; ++k) m += fmaxf(W1[k], 0.0f) * W2[k * 8 + c];
            r += fmaxf(m, 0.0f) * Wlast[c * 8 + j];
        }
        out[i] = Xsum[g] / fmaxf(counts[g], 1.0f) * r;
    }
}

// ---------------- launch ----------------

extern "C" void kernel_launch(void* const* d_in, const int* in_sizes, int n_in,
                              void* d_out, int out_size, void* d_ws, size_t ws_size,
                              hipStream_t stream) {
    const float* W1        = (const float*)d_in[0];
    const float* W2        = (const float*)d_in[1];
    const float* Wlast     = (const float*)d_in[2];
    const int*   src       = (const int*)d_in[3];
    const int*   dst       = (const int*)d_in[4];
    const int*   graph_ids = (const int*)d_in[5];
    float* out = (float*)d_out;

    const int E = in_sizes[3];
    const int N = in_sizes[5];
    const int G = out_size / 8;

    int NB   = (N + BNODES - 1) >> BSH;
    int Npad = NB << BSH;
    int NCH  = (E + SCH - 1) / SCH;
    // Per-bucket capacity: mean + 8192 (~20 sigma for E=10M random), 512-aligned.
    unsigned CAP = (unsigned)(((E / (NB > 0 ? NB : 1)) + 8192 + 511) & ~511);

    // Pick largest J in {8,4,2,1} whose layout fits ws.
    int Jlg = 3;
    size_t req = 0;
    size_t o_dstP, o_srcP, o_curD, o_curS, o_part, o_pio, o_h0sar, o_isi, o_Xsum;
    for (;; --Jlg) {
        int J = 1 << Jlg;
        size_t off = 0;
        auto A = [&](size_t bytes) { size_t o = off; off = (off + bytes + 127) & ~(size_t)127; return o; };
        o_dstP  = A((size_t)NB * CAP * 4);
        o_srcP  = A((size_t)NB * CAP * 2);
        o_curD  = A((size_t)NB * 4);
        o_curS  = A((size_t)NB * 4);
        o_part  = A((size_t)NB * J * BNODES * 4);  // pDeg -> pC -> pT (aliased)
        o_pio   = A((size_t)Npad * 4);
        o_h0sar = A((size_t)Npad * 4);             // h0s -> sarr (aliased)
        o_isi   = A((size_t)Npad * 4);
        o_Xsum  = A((size_t)G * 4);
        req = off;
        if (req <= ws_size || Jlg == 0) break;
    }

    bool fast = (N <= (1 << 19)) && (NB <= MAXNB) && (ws_size >= req) && (E >= 1);

    char* bp = (char*)d_ws;

    if (fast) {
        unsigned*       dstP = (unsigned*)(bp + o_dstP);
        unsigned short* srcP = (unsigned short*)(bp + o_srcP);
        unsigned* curD = (unsigned*)(bp + o_curD);
        unsigned* curS = (unsigned*)(bp + o_curS);
        unsigned* pDeg = (unsigned*)(bp + o_part);
        float*    pC   = (float*)(bp + o_part);
        float*    pT   = (float*)(bp + o_part);
        float* pio  = (float*)(bp + o_pio);
        float* h0s  = (float*)(bp + o_h0sar);
        float* sarr = (float*)(bp + o_h0sar);
        float* isiA = (float*)(bp + o_isi);
        float* Xsum = (float*)(bp + o_Xsum);

        int gridNp = (Npad + TB - 1) / TB;
        int gridN  = (N + TB - 1) / TB;
        int J = 1 << Jlg;
        int gridI = (max(NB, G) + TB - 1) / TB;

        init_kernel<<<gridI, TB, 0, stream>>>(curD, curS, Xsum, NB, CAP, G);
        scatter_sort_kernel<<<NCH, TB, 0, stream>>>(src, dst, curD, curS, dstP, srcP, NB, E);
        deghist_kernel<<<NB * J, TB, 0, stream>>>(srcP, dstP, curS, curD, CAP, pDeg, Jlg);
        prep_kernel<<<gridNp, TB, 0, stream>>>(pDeg, pio, h0s, isiA, Jlg, Npad);
        wh_kernel<<<NB * J, TB, 0, stream>>>(dstP, curD, CAP, h0s, pC, Jlg);
        mid_kernel<<<gridNp, TB, 0, stream>>>(pC, pio, sarr, Jlg, Npad);
        wh_kernel<<<NB * J, TB, 0, stream>>>(dstP, curD, CAP, sarr, pT, Jlg);
        poolfinal_kernel<<<gridN, TB, 0, stream>>>(pT, isiA, graph_ids, Xsum, Jlg, N);
        final_kernel<<<(out_size + TB - 1) / TB, TB, 0, stream>>>(Xsum, graph_ids,
                                                                  W1, W2, Wlast, out, N, out_size);
    } else {
        float* ws = (float*)d_ws;
        size_t f = 0;
        auto FA = [&](size_t n) { size_t o = f; f += (n + 3) & ~(size_t)3; return o; };
        size_t f_degin  = FA(N);
        size_t f_degout = FA(N);
        size_t f_agg1   = FA(N);
        size_t f_t2     = FA(N);
        size_t f_Xsum   = FA(G);
        size_t f_cnt    = FA(G);
        size_t zf = f;
        size_t f_isi = FA(N);
        size_t f_iso = FA(N);
        size_t f_h0s = FA(N);
        size_t f_s   = FA(N);
        hipMemsetAsync(ws, 0, zf * sizeof(float), stream);
        int gridE = (E + TB - 1) / TB;
        int gridN = (N + TB - 1) / TB;
        int gridO = (out_size + TB - 1) / TB;
        fb_deg_kernel<<<gridE, TB, 0, stream>>>(src, dst, ws + f_degout, ws + f_degin, E);
        fb_prep_kernel<<<gridN, TB, 0, stream>>>(ws + f_degin, ws + f_degout,
                                                 ws + f_isi, ws + f_iso, ws + f_h0s, N);
        fb_conv_kernel<<<gridE, TB, 0, stream>>>(src, dst, ws + f_h0s, ws + f_agg1, E);
        fb_mid_kernel<<<gridN, TB, 0, stream>>>(ws + f_agg1, ws + f_isi, ws + f_iso, ws + f_s, N);
        fb_conv_kernel<<<gridE, TB, 0, stream>>>(src, dst, ws + f_s, ws + f_t2, E);
        fb_pool_kernel<<<gridN, TB, 0, stream>>>(ws + f_t2, ws + f_isi, graph_ids,
                                                 ws + f_Xsum, ws + f_cnt, N);
        fb_final_kernel<<<gridO, TB, 0, stream>>>(ws + f_Xsum, ws + f_cnt, W1, W2, Wlast,
                                                  out, out_size);
    }
}